// Round 9
// baseline (579.022 us; speedup 1.0000x reference)
//
#include <hip/hip_runtime.h>

// ---------------------------------------------------------------------------
// GATv2 (2 layers) + mean-pool + MLP for MI355X. fp32 throughout.
// N=50000 nodes, E=800000 edges (+N self loops), IN=128, HID=64, HEADS=2,
// OUT=3, 64 graphs. Output: [64,3] float32.
// R1: k_agg2 pool atomic storm fixed (LDS pre-reduction). 1128 -> 803 us.
// R2: CSR + per-node online softmax; edge phases fused.   803 -> 515 us.
// R3: fused1 2-edge ILP + reg src cache + W2-proj fused.   515 -> 394 us.
// R4: fused1 2 nodes/wave + 4-edge ILP + batched softmax.  394 -> 368 us.
// R5: gemm 128x128 reg-blocked (LDS 72KB->16KB).            368 -> 343 us.
// R6: DPP rotate-reduce + exp2 domain; gemm 64x128/4x8.     343 -> 337 us.
// R7: 8-edge unroll FAILED flat: VGPR 32->52, occupancy 68->35 cancelled the
//     instr savings. fused1 sits at 197MB / ~3.15 TB/s = its gather ceiling.
// R8: revert to 4-edge body (VGPR 32) + DEGREE-SORTED node pairing (k_scan
//     builds 64-bin histogram, k_order counting-sorts; wave halves get equal
//     degree -> phantom-edge waste ~0, big blocks first). k_fill direct-slot
//     atomic (cursor preloaded = row_ptr in k_scan).
// ---------------------------------------------------------------------------

#define NGRAPH 64
#define LOG2E 1.4426950408889634f

// v_mov_dpp row_ror:k (16-lane rows). Valid reduce permutation for
// commutative ops; leaves every lane of the row with the full result.
#define DPP_ROR(C, x) \
  __int_as_float(__builtin_amdgcn_update_dpp(0, __float_as_int(x), (0x120 | C), 0xF, 0xF, false))

__device__ __forceinline__ float rowsum16(float v) {
  v += DPP_ROR(8, v);
  v += DPP_ROR(4, v);
  v += DPP_ROR(2, v);
  v += DPP_ROR(1, v);
  return v;
}

// ---------------------------------------------------------------------------
__global__ void k_deg(const int* __restrict__ ei, int E, int Et, int* __restrict__ deg) {
  int e = blockIdx.x * blockDim.x + threadIdx.x;
  if (e >= Et) return;
  int d = (e < E) ? ei[E + e] : (e - E);  // dst only
  atomicAdd(&deg[d], 1);
}

// single block, 1024 threads: exclusive scan of deg -> row_ptr[0..n],
// cursor = copy of row_ptr (for k_fill's direct-slot atomic), and a 64-bin
// degree histogram -> DESCENDING bin cursors (for k_order counting sort).
__global__ __launch_bounds__(1024) void k_scan(const int* __restrict__ deg,
                                               int* __restrict__ row_ptr,
                                               int* __restrict__ cursor,
                                               int* __restrict__ histcur, int n) {
  __shared__ int sdata[1024];
  __shared__ int hist[64];
  int t = threadIdx.x;
  if (t < 64) hist[t] = 0;
  __syncthreads();
  const int chunk = 52;
  int base = t * chunk;
  int end = min(base + chunk, n);
  int sum = 0;
  for (int i = base; i < end; ++i) {
    int d = deg[i];
    sum += d;
    atomicAdd(&hist[min(d, 63)], 1);
  }
  sdata[t] = sum;
  __syncthreads();
  for (int off = 1; off < 1024; off <<= 1) {
    int v = (t >= off) ? sdata[t - off] : 0;
    __syncthreads();
    sdata[t] += v;
    __syncthreads();
  }
  if (t == 0) {  // descending-degree bin offsets
    int run = 0;
#pragma unroll
    for (int d = 63; d >= 0; --d) {
      int h = hist[d];
      hist[d] = run;
      run += h;
    }
  }
  __syncthreads();
  if (t < 64) histcur[t] = hist[t];
  int run = sdata[t] - sum;  // exclusive prefix of this chunk
  for (int i = base; i < end; ++i) {
    row_ptr[i] = run;
    cursor[i] = run;
    run += deg[i];
  }
  if (t == 1023) row_ptr[n] = sdata[1023];
}

// counting-sort scatter: order[] = nodes in descending-degree bins
__global__ void k_order(const int* __restrict__ deg, int* __restrict__ histcur,
                        int* __restrict__ order, int n) {
  int i = blockIdx.x * blockDim.x + threadIdx.x;
  if (i >= n) return;
  int pos = atomicAdd(&histcur[min(deg[i], 63)], 1);
  order[pos] = i;
}

__global__ void k_fill(const int* __restrict__ ei, int E, int Et,
                       int* __restrict__ cursor, int* __restrict__ csr_src) {
  int e = blockIdx.x * blockDim.x + threadIdx.x;
  if (e >= Et) return;
  int s, d;
  if (e < E) { s = ei[e]; d = ei[E + e]; }
  else       { s = e - E; d = s; }
  int slot = atomicAdd(&cursor[d], 1);  // cursor pre-loaded with row_ptr
  csr_src[slot] = s;
}

// ---------------------------------------------------------------------------
// out[n,128] = x[n,128] @ W[128,128], blockIdx.y selects Wl/Wr.
// 64x128 block tile, BK=16, 256 threads, 4x8 micro-tile.
__global__ __launch_bounds__(256) void k_gemm128(const float* __restrict__ x,
                                                 const float* __restrict__ Wl,
                                                 const float* __restrict__ Wr,
                                                 float* __restrict__ outl,
                                                 float* __restrict__ outr, int n) {
  __shared__ __align__(16) float xs[16][68];   // x tile transposed: [k][row]
  __shared__ __align__(16) float ws[16][132];  // W tile: [k][col]
  const float* W = blockIdx.y ? Wr : Wl;
  float* out = blockIdx.y ? outr : outl;
  int t = threadIdx.x;
  int tx = t & 15, ty = t >> 4;
  int r0 = blockIdx.x * 64;
  float acc[4][8] = {};

  int sr = t >> 2;           // x staging: row 0..63
  int sk = (t & 3) * 4;      // k-quad
  int wk = t >> 5;           // W staging: k row 0..7
  int wc = (t & 31) * 4;     // col quad

  for (int k0 = 0; k0 < 128; k0 += 16) {
    int gr = r0 + sr;
    float4 xv = make_float4(0.f, 0.f, 0.f, 0.f);
    if (gr < n) xv = *(const float4*)&x[(size_t)gr * 128 + k0 + sk];
    float4 wv0 = *(const float4*)&W[(size_t)(k0 + wk) * 128 + wc];
    float4 wv1 = *(const float4*)&W[(size_t)(k0 + wk + 8) * 128 + wc];
    __syncthreads();
    xs[sk + 0][sr] = xv.x;
    xs[sk + 1][sr] = xv.y;
    xs[sk + 2][sr] = xv.z;
    xs[sk + 3][sr] = xv.w;
    *(float4*)&ws[wk][wc] = wv0;
    *(float4*)&ws[wk + 8][wc] = wv1;
    __syncthreads();
#pragma unroll
    for (int k = 0; k < 16; ++k) {
      float4 av = *(const float4*)&xs[k][ty * 4];
      float4 b0 = *(const float4*)&ws[k][tx * 4];
      float4 b1 = *(const float4*)&ws[k][64 + tx * 4];
      float a[4] = {av.x, av.y, av.z, av.w};
      float b[8] = {b0.x, b0.y, b0.z, b0.w, b1.x, b1.y, b1.z, b1.w};
#pragma unroll
      for (int i = 0; i < 4; ++i)
#pragma unroll
        for (int j = 0; j < 8; ++j)
          acc[i][j] = fmaf(a[i], b[j], acc[i][j]);
    }
  }
#pragma unroll
  for (int i = 0; i < 4; ++i) {
    int gr = r0 + ty * 4 + i;
    if (gr < n) {
      *(float4*)&out[(size_t)gr * 128 + tx * 4] =
          make_float4(acc[i][0], acc[i][1], acc[i][2], acc[i][3]);
      *(float4*)&out[(size_t)gr * 128 + 64 + tx * 4] =
          make_float4(acc[i][4], acc[i][5], acc[i][6], acc[i][7]);
    }
  }
}

// ---------------------------------------------------------------------------
// fused layer-1 edge phase + layer-2 input projection.
// TWO nodes per wave, picked via degree-sorted order[]: lanes 0-31 = node
// order[2w], 32-63 = node order[2w+1] (near-equal degree). Lane holds 4
// channels; 16-lane head groups = DPP rows. 4 edges/iter: clamp-free main
// loop to mindeg, clamped+masked tail to maxdeg (tiny after sorting).
__global__ __launch_bounds__(256) void k_fused1(const float* __restrict__ xl,
                                                const float* __restrict__ xr,
                                                const int* __restrict__ row_ptr,
                                                const int* __restrict__ csr_src,
                                                const int* __restrict__ order,
                                                const float* __restrict__ att1,
                                                const float* __restrict__ b1,
                                                const float* __restrict__ W2l,
                                                const float* __restrict__ W2r,
                                                float* __restrict__ xl2,
                                                float* __restrict__ xr2, int n) {
  int wid  = (blockIdx.x * 256 + threadIdx.x) >> 6;
  int lane = threadIdx.x & 63;
  int sub  = lane & 31;
  int idx  = min(wid * 2 + (lane >> 5), n - 1);  // dup of last node is benign
  int node = order[idx];
  int ch = sub * 4;
  const char* xlb = (const char*)xl;
  unsigned chb = (unsigned)ch * 4u;
  float4 xrv = *(const float4*)&xr[(size_t)node * 128 + ch];
  float4 atv = *(const float4*)&att1[ch];
  atv.x *= LOG2E; atv.y *= LOG2E; atv.z *= LOG2E; atv.w *= LOG2E;
  int s0 = row_ptr[node];
  int deg = row_ptr[node + 1] - s0;  // >=1 (self-loop)
  int odeg = __shfl_xor(deg, 32);
  int mindeg = min(deg, odeg);  // wave-uniform
  int maxdeg = max(deg, odeg);  // wave-uniform
  const int* sp = csr_src + s0;

  float m = -1e30f, l = 0.f;
  float4 acc = make_float4(0.f, 0.f, 0.f, 0.f);

  float t0, t1, t2, t3;
#define LOGIT(p, v)                                                     \
    t0 = v.x + xrv.x; t0 = fmaxf(t0, 0.2f * t0);                        \
    t1 = v.y + xrv.y; t1 = fmaxf(t1, 0.2f * t1);                        \
    t2 = v.z + xrv.z; t2 = fmaxf(t2, 0.2f * t2);                        \
    t3 = v.w + xrv.w; t3 = fmaxf(t3, 0.2f * t3);                        \
    p = fmaf(t3, atv.w, fmaf(t2, atv.z, fmaf(t1, atv.y, t0 * atv.x)));

#define BODY(CLAMPED)                                                   \
  {                                                                     \
    int sA, sB, sC, sD;                                                 \
    if (CLAMPED) {                                                      \
      int dm1 = deg - 1;                                                \
      sA = sp[min(e + 0, dm1)];                                         \
      sB = sp[min(e + 1, dm1)];                                         \
      sC = sp[min(e + 2, dm1)];                                         \
      sD = sp[min(e + 3, dm1)];                                         \
    } else {                                                            \
      sA = sp[e + 0]; sB = sp[e + 1]; sC = sp[e + 2]; sD = sp[e + 3];   \
    }                                                                   \
    float4 xa = *(const float4*)(xlb + (((unsigned)sA << 9) + chb));    \
    float4 xb = *(const float4*)(xlb + (((unsigned)sB << 9) + chb));    \
    float4 xc = *(const float4*)(xlb + (((unsigned)sC << 9) + chb));    \
    float4 xd = *(const float4*)(xlb + (((unsigned)sD << 9) + chb));    \
    float pa, pb, pc, pd;                                               \
    LOGIT(pa, xa) LOGIT(pb, xb) LOGIT(pc, xc) LOGIT(pd, xd)             \
    pa = rowsum16(pa);                                                  \
    pb = rowsum16(pb);                                                  \
    pc = rowsum16(pc);                                                  \
    pd = rowsum16(pd);                                                  \
    if (CLAMPED) {                                                      \
      pa = (e + 0 < deg) ? pa : -1e30f;                                 \
      pb = (e + 1 < deg) ? pb : -1e30f;                                 \
      pc = (e + 2 < deg) ? pc : -1e30f;                                 \
      pd = (e + 3 < deg) ? pd : -1e30f;                                 \
    }                                                                   \
    float mn = fmaxf(m, fmaxf(fmaxf(pa, pb), fmaxf(pc, pd)));           \
    float sc = exp2f(m - mn);                                           \
    float wa = exp2f(pa - mn);                                          \
    float wb = exp2f(pb - mn);                                          \
    float wc = exp2f(pc - mn);                                          \
    float wd = exp2f(pd - mn);                                          \
    acc.x = fmaf(wd, xd.x, fmaf(wc, xc.x, fmaf(wb, xb.x, fmaf(wa, xa.x, acc.x * sc)))); \
    acc.y = fmaf(wd, xd.y, fmaf(wc, xc.y, fmaf(wb, xb.y, fmaf(wa, xa.y, acc.y * sc)))); \
    acc.z = fmaf(wd, xd.z, fmaf(wc, xc.z, fmaf(wb, xb.z, fmaf(wa, xa.z, acc.z * sc)))); \
    acc.w = fmaf(wd, xd.w, fmaf(wc, xc.w, fmaf(wb, xb.w, fmaf(wa, xa.w, acc.w * sc)))); \
    l = fmaf(l, sc, wa + wb + wc + wd);                                 \
    m = mn;                                                             \
  }

  int e = 0;
  for (; e + 4 <= mindeg; e += 4) BODY(false)
  for (; e < maxdeg; e += 4) BODY(true)
#undef BODY
#undef LOGIT

  float inv = 1.f / (l + 1e-16f);
  float4 b1v = *(const float4*)&b1[ch];
  float4 h;
  h.x = acc.x * inv + b1v.x; h.x = h.x > 0.f ? h.x : expm1f(h.x);
  h.y = acc.y * inv + b1v.y; h.y = h.y > 0.f ? h.y : expm1f(h.y);
  h.z = acc.z * inv + b1v.z; h.z = h.z > 0.f ? h.z : expm1f(h.z);
  h.w = acc.w * inv + b1v.w; h.w = h.w > 0.f ? h.w : expm1f(h.w);

  float4 u0 = *(const float4*)&W2l[ch * 3 + 0];
  float4 u1 = *(const float4*)&W2l[ch * 3 + 4];
  float4 u2 = *(const float4*)&W2l[ch * 3 + 8];
  float al0 = fmaf(h.w, u2.y, fmaf(h.z, u1.z, fmaf(h.y, u0.w, h.x * u0.x)));
  float al1 = fmaf(h.w, u2.z, fmaf(h.z, u1.w, fmaf(h.y, u1.x, h.x * u0.y)));
  float al2 = fmaf(h.w, u2.w, fmaf(h.z, u2.x, fmaf(h.y, u1.y, h.x * u0.z)));
  float4 v0 = *(const float4*)&W2r[ch * 3 + 0];
  float4 v1 = *(const float4*)&W2r[ch * 3 + 4];
  float4 v2 = *(const float4*)&W2r[ch * 3 + 8];
  float ar0 = fmaf(h.w, v2.y, fmaf(h.z, v1.z, fmaf(h.y, v0.w, h.x * v0.x)));
  float ar1 = fmaf(h.w, v2.z, fmaf(h.z, v1.w, fmaf(h.y, v1.x, h.x * v0.y)));
  float ar2 = fmaf(h.w, v2.w, fmaf(h.z, v2.x, fmaf(h.y, v1.y, h.x * v0.z)));
#pragma unroll
  for (int off = 1; off < 32; off <<= 1) {
    al0 += __shfl_xor(al0, off); al1 += __shfl_xor(al1, off);
    al2 += __shfl_xor(al2, off); ar0 += __shfl_xor(ar0, off);
    ar1 += __shfl_xor(ar1, off); ar2 += __shfl_xor(ar2, off);
  }
  if (sub == 0) {
    *(float4*)&xl2[node * 4] = make_float4(al0, al1, al2, 0.f);
    *(float4*)&xr2[node * 4] = make_float4(ar0, ar1, ar2, 0.f);
  }
}

// ---------------------------------------------------------------------------
// fused layer-2 edge phase + mean-pool. 16 lanes per node (= one DPP row);
// per-lane online softmax (exp2 domain) over a 16-stride slice, DPP rotate
// merge of (m,l,acc3) states. Pool pre-reduced in LDS.
__global__ __launch_bounds__(256) void k_fused2(const float* __restrict__ xl2,
                                                const float* __restrict__ xr2,
                                                const int* __restrict__ row_ptr,
                                                const int* __restrict__ csr_src,
                                                const float* __restrict__ att2,
                                                const float* __restrict__ b2,
                                                const int* __restrict__ batch,
                                                float* __restrict__ gsum,
                                                float* __restrict__ gcnt, int n) {
  __shared__ float ls[NGRAPH * 3];
  __shared__ float lc[NGRAPH];
  int t = threadIdx.x;
  for (int i = t; i < NGRAPH * 3; i += 256) ls[i] = 0.f;
  for (int i = t; i < NGRAPH; i += 256) lc[i] = 0.f;
  __syncthreads();

  int node = (blockIdx.x * 256 + t) >> 4;  // 16 nodes per block
  int lane = t & 15;
  if (node < n) {
    float4 xrv = *(const float4*)&xr2[node * 4];
    float c0 = att2[0] * LOG2E, c1 = att2[1] * LOG2E, c2 = att2[2] * LOG2E;
    int s0 = row_ptr[node], s1 = row_ptr[node + 1];
    float m = -1e30f, l = 0.f, a0 = 0.f, a1 = 0.f, a2 = 0.f;
    for (int slot = s0 + lane; slot < s1; slot += 16) {
      int s = csr_src[slot];
      float4 xlv = *(const float4*)&xl2[s * 4];
      float t0 = xlv.x + xrv.x; t0 = fmaxf(t0, 0.2f * t0);
      float t1 = xlv.y + xrv.y; t1 = fmaxf(t1, 0.2f * t1);
      float t2 = xlv.z + xrv.z; t2 = fmaxf(t2, 0.2f * t2);
      float p = fmaf(t2, c2, fmaf(t1, c1, t0 * c0));
      float mn = fmaxf(m, p);
      float sc = exp2f(m - mn);
      float w  = exp2f(p - mn);
      a0 = a0 * sc + w * xlv.x;
      a1 = a1 * sc + w * xlv.y;
      a2 = a2 * sc + w * xlv.z;
      l = l * sc + w;
      m = mn;
    }
#define MERGE(C)                                                        \
    {                                                                   \
      float m2 = DPP_ROR(C, m);                                         \
      float l2 = DPP_ROR(C, l);                                         \
      float b0 = DPP_ROR(C, a0);                                        \
      float b1v = DPP_ROR(C, a1);                                       \
      float b2v = DPP_ROR(C, a2);                                       \
      float mn = fmaxf(m, m2);                                          \
      float sA = exp2f(m - mn);                                         \
      float sB = exp2f(m2 - mn);                                        \
      a0 = a0 * sA + b0 * sB;                                           \
      a1 = a1 * sA + b1v * sB;                                          \
      a2 = a2 * sA + b2v * sB;                                          \
      l = l * sA + l2 * sB;                                             \
      m = mn;                                                           \
    }
    MERGE(8) MERGE(4) MERGE(2) MERGE(1)
#undef MERGE
    if (lane == 0) {
      float inv = 1.f / (l + 1e-16f);
      float o0 = a0 * inv + b2[0];
      float o1 = a1 * inv + b2[1];
      float o2 = a2 * inv + b2[2];
      int b = batch[node];
      atomicAdd(&ls[b * 3 + 0], o0);
      atomicAdd(&ls[b * 3 + 1], o1);
      atomicAdd(&ls[b * 3 + 2], o2);
      atomicAdd(&lc[b], 1.f);
    }
  }
  __syncthreads();
  for (int i = t; i < NGRAPH * 3; i += 256)
    if (ls[i] != 0.f) atomicAdd(&gsum[i], ls[i]);
  for (int i = t; i < NGRAPH; i += 256)
    if (lc[i] != 0.f) atomicAdd(&gcnt[i], lc[i]);
}

// 1 block, 64 threads: per-graph mean + 2-layer MLP
__global__ __launch_bounds__(64) void k_mlp(const float* __restrict__ gsum,
                                            const float* __restrict__ gcnt,
                                            const float* __restrict__ Wr1,
                                            const float* __restrict__ br1,
                                            const float* __restrict__ Wr2,
                                            const float* __restrict__ br2,
                                            float* __restrict__ out) {
  int t = threadIdx.x;
  if (t >= NGRAPH) return;
  float cnt = fmaxf(gcnt[t], 1.f);
  float g0 = gsum[t * 3 + 0] / cnt;
  float g1 = gsum[t * 3 + 1] / cnt;
  float g2 = gsum[t * 3 + 2] / cnt;
  float o0 = br2[0], o1 = br2[1], o2 = br2[2];
  for (int j = 0; j < 64; ++j) {
    float hj = g0 * Wr1[j] + g1 * Wr1[64 + j] + g2 * Wr1[128 + j] + br1[j];
    hj = fmaxf(hj, 0.f);
    o0 = fmaf(hj, Wr2[j * 3 + 0], o0);
    o1 = fmaf(hj, Wr2[j * 3 + 1], o1);
    o2 = fmaf(hj, Wr2[j * 3 + 2], o2);
  }
  out[t * 3 + 0] = o0;
  out[t * 3 + 1] = o1;
  out[t * 3 + 2] = o2;
}

// ---------------------------------------------------------------------------
extern "C" void kernel_launch(void* const* d_in, const int* in_sizes, int n_in,
                              void* d_out, int out_size, void* d_ws, size_t ws_size,
                              hipStream_t stream) {
  const float* x    = (const float*)d_in[0];
  const int*   ei   = (const int*)d_in[1];
  const int*   batch= (const int*)d_in[2];
  const float* W1l  = (const float*)d_in[3];
  const float* W1r  = (const float*)d_in[4];
  const float* att1 = (const float*)d_in[5];
  const float* b1   = (const float*)d_in[6];
  const float* W2l  = (const float*)d_in[7];
  const float* W2r  = (const float*)d_in[8];
  const float* att2 = (const float*)d_in[9];
  const float* b2   = (const float*)d_in[10];
  const float* Wr1  = (const float*)d_in[11];
  const float* br1  = (const float*)d_in[12];
  const float* Wr2  = (const float*)d_in[13];
  const float* br2  = (const float*)d_in[14];
  float* out = (float*)d_out;

  const int N  = in_sizes[0] / 128;
  const int E  = in_sizes[1] / 2;
  const int Et = E + N;

  char* p = (char*)d_ws;
  auto alloc = [&](size_t bytes) -> char* {
    char* r = p;
    p += (bytes + 255) & ~(size_t)255;
    return r;
  };
  float*    xl1    = (float*)alloc((size_t)N * 128 * 4);
  float*    xr1    = (float*)alloc((size_t)N * 128 * 4);
  int*      row_ptr= (int*)alloc((size_t)(N + 1) * 4);
  int*      csr_src= (int*)alloc((size_t)Et * 4);
  int*      cursor = (int*)alloc((size_t)N * 4);
  int*      order  = (int*)alloc((size_t)N * 4);
  int*      histcur= (int*)alloc(64 * 4);
  // zero-init group (one memset): deg | gsum | gcnt
  char*     z0     = p;
  int*      deg    = (int*)alloc((size_t)N * 4);
  float*    gsum   = (float*)alloc(NGRAPH * 3 * 4);
  float*    gcnt   = (float*)alloc(NGRAPH * 4);
  size_t    zbytes = (size_t)(p - z0);
  float*    xl2    = (float*)alloc((size_t)N * 4 * 4);
  float*    xr2    = (float*)alloc((size_t)N * 4 * 4);

  hipMemsetAsync(z0, 0, zbytes, stream);
  hipLaunchKernelGGL(k_deg, dim3((Et + 255) / 256), dim3(256), 0, stream, ei, E, Et, deg);
  hipLaunchKernelGGL(k_scan, dim3(1), dim3(1024), 0, stream,
                     deg, row_ptr, cursor, histcur, N);
  hipLaunchKernelGGL(k_order, dim3((N + 255) / 256), dim3(256), 0, stream,
                     deg, histcur, order, N);
  hipLaunchKernelGGL(k_fill, dim3((Et + 255) / 256), dim3(256), 0, stream,
                     ei, E, Et, cursor, csr_src);
  hipLaunchKernelGGL(k_gemm128, dim3((N + 63) / 64, 2), dim3(256), 0, stream,
                     x, W1l, W1r, xl1, xr1, N);
  int waves1 = (N + 1) / 2;
  hipLaunchKernelGGL(k_fused1, dim3((waves1 * 64 + 255) / 256), dim3(256), 0, stream,
                     xl1, xr1, row_ptr, csr_src, order, att1, b1, W2l, W2r,
                     xl2, xr2, N);
  hipLaunchKernelGGL(k_fused2, dim3((N * 16 + 255) / 256), dim3(256), 0, stream,
                     xl2, xr2, row_ptr, csr_src, att2, b2, batch, gsum, gcnt, N);
  hipLaunchKernelGGL(k_mlp, dim3(1), dim3(64), 0, stream,
                     gsum, gcnt, Wr1, br1, Wr2, br2, out);
}

// Round 10
// 422.734 us; speedup vs baseline: 1.3697x; 1.3697x over previous
//
#include <hip/hip_runtime.h>

// ---------------------------------------------------------------------------
// GATv2 (2 layers) + mean-pool + MLP for MI355X. fp32 throughout.
// N=50000 nodes, E=800000 edges (+N self loops), IN=128, HID=64, HEADS=2,
// OUT=3, 64 graphs. Output: [64,3] float32.
// R1: k_agg2 pool atomic storm fixed (LDS pre-reduction). 1128 -> 803 us.
// R2: CSR + per-node online softmax; edge phases fused.   803 -> 515 us.
// R3: fused1 2-edge ILP + reg src cache + W2-proj fused.   515 -> 394 us.
// R4: fused1 2 nodes/wave + 4-edge ILP + batched softmax.  394 -> 368 us.
// R5: gemm 128x128 reg-blocked (LDS 72KB->16KB).            368 -> 343 us.
// R6: DPP rotate-reduce + exp2 domain; gemm 64x128/4x8.     343 -> 337 us.
// R7: 8-edge unroll flat (VGPR 52, occ 35 cancels savings). 337 -> 335 us.
// R8/R9: degree-sort pairing REGRESSED 335 -> 579: k_order was a 64-address
//     device-atomic storm (140us, occ 8%) + k_scan LDS-atomic hist serialized
//     a single CU. Lesson re-learned: fused1 is FETCH-bound (197MB @ 3.15TB/s
//     = its 64us), so cutting phantom-edge VALU work was the wrong lever.
//     REVERTED to R7-best; kept only k_fill direct-slot (cursor=row_ptr).
// ---------------------------------------------------------------------------

#define NGRAPH 64
#define LOG2E 1.4426950408889634f

// v_mov_dpp row_ror:k (16-lane rows). Valid reduce permutation for
// commutative ops; leaves every lane of the row with the full result.
#define DPP_ROR(C, x) \
  __int_as_float(__builtin_amdgcn_update_dpp(0, __float_as_int(x), (0x120 | C), 0xF, 0xF, false))

__device__ __forceinline__ float rowsum16(float v) {
  v += DPP_ROR(8, v);
  v += DPP_ROR(4, v);
  v += DPP_ROR(2, v);
  v += DPP_ROR(1, v);
  return v;
}

// ---------------------------------------------------------------------------
__global__ void k_deg(const int* __restrict__ ei, int E, int Et, int* __restrict__ deg) {
  int e = blockIdx.x * blockDim.x + threadIdx.x;
  if (e >= Et) return;
  int d = (e < E) ? ei[E + e] : (e - E);  // dst only
  atomicAdd(&deg[d], 1);
}

// single block, 1024 threads: exclusive scan of deg -> row_ptr[0..n];
// cursor = copy of row_ptr (k_fill's direct-slot atomic).
__global__ __launch_bounds__(1024) void k_scan(const int* __restrict__ deg,
                                               int* __restrict__ row_ptr,
                                               int* __restrict__ cursor, int n) {
  __shared__ int sdata[1024];
  int t = threadIdx.x;
  const int chunk = 52;
  int base = t * chunk;
  int end = min(base + chunk, n);
  int sum = 0;
  if (base + chunk <= n) {
#pragma unroll
    for (int i = 0; i < 13; ++i) {
      int4 d = *(const int4*)&deg[base + i * 4];
      sum += d.x + d.y + d.z + d.w;
    }
  } else {
    for (int i = base; i < end; ++i) sum += deg[i];
  }
  sdata[t] = sum;
  __syncthreads();
  for (int off = 1; off < 1024; off <<= 1) {
    int v = (t >= off) ? sdata[t - off] : 0;
    __syncthreads();
    sdata[t] += v;
    __syncthreads();
  }
  int run = sdata[t] - sum;  // exclusive prefix of this chunk
  for (int i = base; i < end; ++i) {
    row_ptr[i] = run;
    cursor[i] = run;
    run += deg[i];
  }
  if (t == 1023) row_ptr[n] = sdata[1023];
}

__global__ void k_fill(const int* __restrict__ ei, int E, int Et,
                       int* __restrict__ cursor, int* __restrict__ csr_src) {
  int e = blockIdx.x * blockDim.x + threadIdx.x;
  if (e >= Et) return;
  int s, d;
  if (e < E) { s = ei[e]; d = ei[E + e]; }
  else       { s = e - E; d = s; }
  int slot = atomicAdd(&cursor[d], 1);  // cursor pre-loaded with row_ptr
  csr_src[slot] = s;
}

// ---------------------------------------------------------------------------
// out[n,128] = x[n,128] @ W[128,128], blockIdx.y selects Wl/Wr.
// 64x128 block tile, BK=16, 256 threads, 4x8 micro-tile.
__global__ __launch_bounds__(256) void k_gemm128(const float* __restrict__ x,
                                                 const float* __restrict__ Wl,
                                                 const float* __restrict__ Wr,
                                                 float* __restrict__ outl,
                                                 float* __restrict__ outr, int n) {
  __shared__ __align__(16) float xs[16][68];   // x tile transposed: [k][row]
  __shared__ __align__(16) float ws[16][132];  // W tile: [k][col]
  const float* W = blockIdx.y ? Wr : Wl;
  float* out = blockIdx.y ? outr : outl;
  int t = threadIdx.x;
  int tx = t & 15, ty = t >> 4;
  int r0 = blockIdx.x * 64;
  float acc[4][8] = {};

  int sr = t >> 2;           // x staging: row 0..63
  int sk = (t & 3) * 4;      // k-quad
  int wk = t >> 5;           // W staging: k row 0..7
  int wc = (t & 31) * 4;     // col quad

  for (int k0 = 0; k0 < 128; k0 += 16) {
    int gr = r0 + sr;
    float4 xv = make_float4(0.f, 0.f, 0.f, 0.f);
    if (gr < n) xv = *(const float4*)&x[(size_t)gr * 128 + k0 + sk];
    float4 wv0 = *(const float4*)&W[(size_t)(k0 + wk) * 128 + wc];
    float4 wv1 = *(const float4*)&W[(size_t)(k0 + wk + 8) * 128 + wc];
    __syncthreads();
    xs[sk + 0][sr] = xv.x;
    xs[sk + 1][sr] = xv.y;
    xs[sk + 2][sr] = xv.z;
    xs[sk + 3][sr] = xv.w;
    *(float4*)&ws[wk][wc] = wv0;
    *(float4*)&ws[wk + 8][wc] = wv1;
    __syncthreads();
#pragma unroll
    for (int k = 0; k < 16; ++k) {
      float4 av = *(const float4*)&xs[k][ty * 4];
      float4 b0 = *(const float4*)&ws[k][tx * 4];
      float4 b1 = *(const float4*)&ws[k][64 + tx * 4];
      float a[4] = {av.x, av.y, av.z, av.w};
      float b[8] = {b0.x, b0.y, b0.z, b0.w, b1.x, b1.y, b1.z, b1.w};
#pragma unroll
      for (int i = 0; i < 4; ++i)
#pragma unroll
        for (int j = 0; j < 8; ++j)
          acc[i][j] = fmaf(a[i], b[j], acc[i][j]);
    }
  }
#pragma unroll
  for (int i = 0; i < 4; ++i) {
    int gr = r0 + ty * 4 + i;
    if (gr < n) {
      *(float4*)&out[(size_t)gr * 128 + tx * 4] =
          make_float4(acc[i][0], acc[i][1], acc[i][2], acc[i][3]);
      *(float4*)&out[(size_t)gr * 128 + 64 + tx * 4] =
          make_float4(acc[i][4], acc[i][5], acc[i][6], acc[i][7]);
    }
  }
}

// ---------------------------------------------------------------------------
// fused layer-1 edge phase + layer-2 input projection.
// TWO nodes per wave: lanes 0-31 = node 2w, 32-63 = node 2w+1. Lane holds 4
// channels; 16-lane head groups = DPP rows. 4 edges/iter: clamp-free main
// loop to mindeg, clamped+masked tail to maxdeg.
__global__ __launch_bounds__(256) void k_fused1(const float* __restrict__ xl,
                                                const float* __restrict__ xr,
                                                const int* __restrict__ row_ptr,
                                                const int* __restrict__ csr_src,
                                                const float* __restrict__ att1,
                                                const float* __restrict__ b1,
                                                const float* __restrict__ W2l,
                                                const float* __restrict__ W2r,
                                                float* __restrict__ xl2,
                                                float* __restrict__ xr2, int n) {
  int wid  = (blockIdx.x * 256 + threadIdx.x) >> 6;
  int lane = threadIdx.x & 63;
  int sub  = lane & 31;
  int node = min(wid * 2 + (lane >> 5), n - 1);  // dup of last node is benign
  int ch = sub * 4;
  const char* xlb = (const char*)xl;
  unsigned chb = (unsigned)ch * 4u;
  float4 xrv = *(const float4*)&xr[(size_t)node * 128 + ch];
  float4 atv = *(const float4*)&att1[ch];
  atv.x *= LOG2E; atv.y *= LOG2E; atv.z *= LOG2E; atv.w *= LOG2E;
  int s0 = row_ptr[node];
  int deg = row_ptr[node + 1] - s0;  // >=1 (self-loop)
  int odeg = __shfl_xor(deg, 32);
  int mindeg = min(deg, odeg);  // wave-uniform
  int maxdeg = max(deg, odeg);  // wave-uniform
  const int* sp = csr_src + s0;

  float m = -1e30f, l = 0.f;
  float4 acc = make_float4(0.f, 0.f, 0.f, 0.f);

  float t0, t1, t2, t3;
#define LOGIT(p, v)                                                     \
    t0 = v.x + xrv.x; t0 = fmaxf(t0, 0.2f * t0);                        \
    t1 = v.y + xrv.y; t1 = fmaxf(t1, 0.2f * t1);                        \
    t2 = v.z + xrv.z; t2 = fmaxf(t2, 0.2f * t2);                        \
    t3 = v.w + xrv.w; t3 = fmaxf(t3, 0.2f * t3);                        \
    p = fmaf(t3, atv.w, fmaf(t2, atv.z, fmaf(t1, atv.y, t0 * atv.x)));

#define BODY(CLAMPED)                                                   \
  {                                                                     \
    int sA, sB, sC, sD;                                                 \
    if (CLAMPED) {                                                      \
      int dm1 = deg - 1;                                                \
      sA = sp[min(e + 0, dm1)];                                         \
      sB = sp[min(e + 1, dm1)];                                         \
      sC = sp[min(e + 2, dm1)];                                         \
      sD = sp[min(e + 3, dm1)];                                         \
    } else {                                                            \
      sA = sp[e + 0]; sB = sp[e + 1]; sC = sp[e + 2]; sD = sp[e + 3];   \
    }                                                                   \
    float4 xa = *(const float4*)(xlb + (((unsigned)sA << 9) + chb));    \
    float4 xb = *(const float4*)(xlb + (((unsigned)sB << 9) + chb));    \
    float4 xc = *(const float4*)(xlb + (((unsigned)sC << 9) + chb));    \
    float4 xd = *(const float4*)(xlb + (((unsigned)sD << 9) + chb));    \
    float pa, pb, pc, pd;                                               \
    LOGIT(pa, xa) LOGIT(pb, xb) LOGIT(pc, xc) LOGIT(pd, xd)             \
    pa = rowsum16(pa);                                                  \
    pb = rowsum16(pb);                                                  \
    pc = rowsum16(pc);                                                  \
    pd = rowsum16(pd);                                                  \
    if (CLAMPED) {                                                      \
      pa = (e + 0 < deg) ? pa : -1e30f;                                 \
      pb = (e + 1 < deg) ? pb : -1e30f;                                 \
      pc = (e + 2 < deg) ? pc : -1e30f;                                 \
      pd = (e + 3 < deg) ? pd : -1e30f;                                 \
    }                                                                   \
    float mn = fmaxf(m, fmaxf(fmaxf(pa, pb), fmaxf(pc, pd)));           \
    float sc = exp2f(m - mn);                                           \
    float wa = exp2f(pa - mn);                                          \
    float wb = exp2f(pb - mn);                                          \
    float wc = exp2f(pc - mn);                                          \
    float wd = exp2f(pd - mn);                                          \
    acc.x = fmaf(wd, xd.x, fmaf(wc, xc.x, fmaf(wb, xb.x, fmaf(wa, xa.x, acc.x * sc)))); \
    acc.y = fmaf(wd, xd.y, fmaf(wc, xc.y, fmaf(wb, xb.y, fmaf(wa, xa.y, acc.y * sc)))); \
    acc.z = fmaf(wd, xd.z, fmaf(wc, xc.z, fmaf(wb, xb.z, fmaf(wa, xa.z, acc.z * sc)))); \
    acc.w = fmaf(wd, xd.w, fmaf(wc, xc.w, fmaf(wb, xb.w, fmaf(wa, xa.w, acc.w * sc)))); \
    l = fmaf(l, sc, wa + wb + wc + wd);                                 \
    m = mn;                                                             \
  }

  int e = 0;
  for (; e + 4 <= mindeg; e += 4) BODY(false)
  for (; e < maxdeg; e += 4) BODY(true)
#undef BODY
#undef LOGIT

  float inv = 1.f / (l + 1e-16f);
  float4 b1v = *(const float4*)&b1[ch];
  float4 h;
  h.x = acc.x * inv + b1v.x; h.x = h.x > 0.f ? h.x : expm1f(h.x);
  h.y = acc.y * inv + b1v.y; h.y = h.y > 0.f ? h.y : expm1f(h.y);
  h.z = acc.z * inv + b1v.z; h.z = h.z > 0.f ? h.z : expm1f(h.z);
  h.w = acc.w * inv + b1v.w; h.w = h.w > 0.f ? h.w : expm1f(h.w);

  float4 u0 = *(const float4*)&W2l[ch * 3 + 0];
  float4 u1 = *(const float4*)&W2l[ch * 3 + 4];
  float4 u2 = *(const float4*)&W2l[ch * 3 + 8];
  float al0 = fmaf(h.w, u2.y, fmaf(h.z, u1.z, fmaf(h.y, u0.w, h.x * u0.x)));
  float al1 = fmaf(h.w, u2.z, fmaf(h.z, u1.w, fmaf(h.y, u1.x, h.x * u0.y)));
  float al2 = fmaf(h.w, u2.w, fmaf(h.z, u2.x, fmaf(h.y, u1.y, h.x * u0.z)));
  float4 v0 = *(const float4*)&W2r[ch * 3 + 0];
  float4 v1 = *(const float4*)&W2r[ch * 3 + 4];
  float4 v2 = *(const float4*)&W2r[ch * 3 + 8];
  float ar0 = fmaf(h.w, v2.y, fmaf(h.z, v1.z, fmaf(h.y, v0.w, h.x * v0.x)));
  float ar1 = fmaf(h.w, v2.z, fmaf(h.z, v1.w, fmaf(h.y, v1.x, h.x * v0.y)));
  float ar2 = fmaf(h.w, v2.w, fmaf(h.z, v2.x, fmaf(h.y, v1.y, h.x * v0.z)));
#pragma unroll
  for (int off = 1; off < 32; off <<= 1) {
    al0 += __shfl_xor(al0, off); al1 += __shfl_xor(al1, off);
    al2 += __shfl_xor(al2, off); ar0 += __shfl_xor(ar0, off);
    ar1 += __shfl_xor(ar1, off); ar2 += __shfl_xor(ar2, off);
  }
  if (sub == 0 && wid * 2 + (lane >> 5) < n) {
    *(float4*)&xl2[node * 4] = make_float4(al0, al1, al2, 0.f);
    *(float4*)&xr2[node * 4] = make_float4(ar0, ar1, ar2, 0.f);
  }
}

// ---------------------------------------------------------------------------
// fused layer-2 edge phase + mean-pool. 16 lanes per node (= one DPP row);
// per-lane online softmax (exp2 domain) over a 16-stride slice, DPP rotate
// merge of (m,l,acc3) states. Pool pre-reduced in LDS.
__global__ __launch_bounds__(256) void k_fused2(const float* __restrict__ xl2,
                                                const float* __restrict__ xr2,
                                                const int* __restrict__ row_ptr,
                                                const int* __restrict__ csr_src,
                                                const float* __restrict__ att2,
                                                const float* __restrict__ b2,
                                                const int* __restrict__ batch,
                                                float* __restrict__ gsum,
                                                float* __restrict__ gcnt, int n) {
  __shared__ float ls[NGRAPH * 3];
  __shared__ float lc[NGRAPH];
  int t = threadIdx.x;
  for (int i = t; i < NGRAPH * 3; i += 256) ls[i] = 0.f;
  for (int i = t; i < NGRAPH; i += 256) lc[i] = 0.f;
  __syncthreads();

  int node = (blockIdx.x * 256 + t) >> 4;  // 16 nodes per block
  int lane = t & 15;
  if (node < n) {
    float4 xrv = *(const float4*)&xr2[node * 4];
    float c0 = att2[0] * LOG2E, c1 = att2[1] * LOG2E, c2 = att2[2] * LOG2E;
    int s0 = row_ptr[node], s1 = row_ptr[node + 1];
    float m = -1e30f, l = 0.f, a0 = 0.f, a1 = 0.f, a2 = 0.f;
    for (int slot = s0 + lane; slot < s1; slot += 16) {
      int s = csr_src[slot];
      float4 xlv = *(const float4*)&xl2[s * 4];
      float t0 = xlv.x + xrv.x; t0 = fmaxf(t0, 0.2f * t0);
      float t1 = xlv.y + xrv.y; t1 = fmaxf(t1, 0.2f * t1);
      float t2 = xlv.z + xrv.z; t2 = fmaxf(t2, 0.2f * t2);
      float p = fmaf(t2, c2, fmaf(t1, c1, t0 * c0));
      float mn = fmaxf(m, p);
      float sc = exp2f(m - mn);
      float w  = exp2f(p - mn);
      a0 = a0 * sc + w * xlv.x;
      a1 = a1 * sc + w * xlv.y;
      a2 = a2 * sc + w * xlv.z;
      l = l * sc + w;
      m = mn;
    }
#define MERGE(C)                                                        \
    {                                                                   \
      float m2 = DPP_ROR(C, m);                                         \
      float l2 = DPP_ROR(C, l);                                         \
      float b0 = DPP_ROR(C, a0);                                        \
      float b1v = DPP_ROR(C, a1);                                       \
      float b2v = DPP_ROR(C, a2);                                       \
      float mn = fmaxf(m, m2);                                          \
      float sA = exp2f(m - mn);                                         \
      float sB = exp2f(m2 - mn);                                        \
      a0 = a0 * sA + b0 * sB;                                           \
      a1 = a1 * sA + b1v * sB;                                          \
      a2 = a2 * sA + b2v * sB;                                          \
      l = l * sA + l2 * sB;                                             \
      m = mn;                                                           \
    }
    MERGE(8) MERGE(4) MERGE(2) MERGE(1)
#undef MERGE
    if (lane == 0) {
      float inv = 1.f / (l + 1e-16f);
      float o0 = a0 * inv + b2[0];
      float o1 = a1 * inv + b2[1];
      float o2 = a2 * inv + b2[2];
      int b = batch[node];
      atomicAdd(&ls[b * 3 + 0], o0);
      atomicAdd(&ls[b * 3 + 1], o1);
      atomicAdd(&ls[b * 3 + 2], o2);
      atomicAdd(&lc[b], 1.f);
    }
  }
  __syncthreads();
  for (int i = t; i < NGRAPH * 3; i += 256)
    if (ls[i] != 0.f) atomicAdd(&gsum[i], ls[i]);
  for (int i = t; i < NGRAPH; i += 256)
    if (lc[i] != 0.f) atomicAdd(&gcnt[i], lc[i]);
}

// 1 block, 64 threads: per-graph mean + 2-layer MLP
__global__ __launch_bounds__(64) void k_mlp(const float* __restrict__ gsum,
                                            const float* __restrict__ gcnt,
                                            const float* __restrict__ Wr1,
                                            const float* __restrict__ br1,
                                            const float* __restrict__ Wr2,
                                            const float* __restrict__ br2,
                                            float* __restrict__ out) {
  int t = threadIdx.x;
  if (t >= NGRAPH) return;
  float cnt = fmaxf(gcnt[t], 1.f);
  float g0 = gsum[t * 3 + 0] / cnt;
  float g1 = gsum[t * 3 + 1] / cnt;
  float g2 = gsum[t * 3 + 2] / cnt;
  float o0 = br2[0], o1 = br2[1], o2 = br2[2];
  for (int j = 0; j < 64; ++j) {
    float hj = g0 * Wr1[j] + g1 * Wr1[64 + j] + g2 * Wr1[128 + j] + br1[j];
    hj = fmaxf(hj, 0.f);
    o0 = fmaf(hj, Wr2[j * 3 + 0], o0);
    o1 = fmaf(hj, Wr2[j * 3 + 1], o1);
    o2 = fmaf(hj, Wr2[j * 3 + 2], o2);
  }
  out[t * 3 + 0] = o0;
  out[t * 3 + 1] = o1;
  out[t * 3 + 2] = o2;
}

// ---------------------------------------------------------------------------
extern "C" void kernel_launch(void* const* d_in, const int* in_sizes, int n_in,
                              void* d_out, int out_size, void* d_ws, size_t ws_size,
                              hipStream_t stream) {
  const float* x    = (const float*)d_in[0];
  const int*   ei   = (const int*)d_in[1];
  const int*   batch= (const int*)d_in[2];
  const float* W1l  = (const float*)d_in[3];
  const float* W1r  = (const float*)d_in[4];
  const float* att1 = (const float*)d_in[5];
  const float* b1   = (const float*)d_in[6];
  const float* W2l  = (const float*)d_in[7];
  const float* W2r  = (const float*)d_in[8];
  const float* att2 = (const float*)d_in[9];
  const float* b2   = (const float*)d_in[10];
  const float* Wr1  = (const float*)d_in[11];
  const float* br1  = (const float*)d_in[12];
  const float* Wr2  = (const float*)d_in[13];
  const float* br2  = (const float*)d_in[14];
  float* out = (float*)d_out;

  const int N  = in_sizes[0] / 128;
  const int E  = in_sizes[1] / 2;
  const int Et = E + N;

  char* p = (char*)d_ws;
  auto alloc = [&](size_t bytes) -> char* {
    char* r = p;
    p += (bytes + 255) & ~(size_t)255;
    return r;
  };
  float*    xl1    = (float*)alloc((size_t)N * 128 * 4);
  float*    xr1    = (float*)alloc((size_t)N * 128 * 4);
  int*      row_ptr= (int*)alloc((size_t)(N + 1) * 4);
  int*      csr_src= (int*)alloc((size_t)Et * 4);
  int*      cursor = (int*)alloc((size_t)N * 4);
  // zero-init group (one memset): deg | gsum | gcnt
  char*     z0     = p;
  int*      deg    = (int*)alloc((size_t)N * 4);
  float*    gsum   = (float*)alloc(NGRAPH * 3 * 4);
  float*    gcnt   = (float*)alloc(NGRAPH * 4);
  size_t    zbytes = (size_t)(p - z0);
  float*    xl2    = (float*)alloc((size_t)N * 4 * 4);
  float*    xr2    = (float*)alloc((size_t)N * 4 * 4);

  hipMemsetAsync(z0, 0, zbytes, stream);
  hipLaunchKernelGGL(k_deg, dim3((Et + 255) / 256), dim3(256), 0, stream, ei, E, Et, deg);
  hipLaunchKernelGGL(k_scan, dim3(1), dim3(1024), 0, stream, deg, row_ptr, cursor, N);
  hipLaunchKernelGGL(k_fill, dim3((Et + 255) / 256), dim3(256), 0, stream,
                     ei, E, Et, cursor, csr_src);
  hipLaunchKernelGGL(k_gemm128, dim3((N + 63) / 64, 2), dim3(256), 0, stream,
                     x, W1l, W1r, xl1, xr1, N);
  int waves1 = (N + 1) / 2;
  hipLaunchKernelGGL(k_fused1, dim3((waves1 * 64 + 255) / 256), dim3(256), 0, stream,
                     xl1, xr1, row_ptr, csr_src, att1, b1, W2l, W2r, xl2, xr2, N);
  hipLaunchKernelGGL(k_fused2, dim3((N * 16 + 255) / 256), dim3(256), 0, stream,
                     xl2, xr2, row_ptr, csr_src, att2, b2, batch, gsum, gcnt, N);
  hipLaunchKernelGGL(k_mlp, dim3(1), dim3(64), 0, stream,
                     gsum, gcnt, Wr1, br1, Wr2, br2, out);
}

// Round 11
// 328.868 us; speedup vs baseline: 1.7607x; 1.2854x over previous
//
#include <hip/hip_runtime.h>

// ---------------------------------------------------------------------------
// GATv2 (2 layers) + mean-pool + MLP for MI355X. fp32 throughout.
// N=50000 nodes, E=800000 edges (+N self loops), IN=128, HID=64, HEADS=2,
// OUT=3, 64 graphs. Output: [64,3] float32.
// R1: k_agg2 pool atomic storm fixed (LDS pre-reduction). 1128 -> 803 us.
// R2: CSR + per-node online softmax; edge phases fused.   803 -> 515 us.
// R3: fused1 2-edge ILP + reg src cache + W2-proj fused.   515 -> 394 us.
// R4: fused1 2 nodes/wave + 4-edge ILP + batched softmax.  394 -> 368 us.
// R5: gemm 128x128 reg-blocked (LDS 72KB->16KB).            368 -> 343 us.
// R6: DPP rotate-reduce + exp2 domain; gemm 64x128/4x8.     343 -> 337 us.
// R7: 8-edge unroll flat (VGPR 52, occ 35 cancels savings). 337 -> 335 us.
// R8/R9: degree-sort pairing REGRESSED (k_order atomic storm + k_scan scalar
//     dual-store). R10 revert still 422: k_scan was 100us — SINGLE BLOCK on
//     1 CU (occupancy 0.14%), a hidden serialization tax since R2.
// R11: 3-phase parallel scan (49-block partial sums -> 1-block top scan ->
//     49-block scatter with int4 stores of row_ptr+cursor). ~100 -> ~7 us.
// ---------------------------------------------------------------------------

#define NGRAPH 64
#define LOG2E 1.4426950408889634f

// v_mov_dpp row_ror:k (16-lane rows). Valid reduce permutation for
// commutative ops; leaves every lane of the row with the full result.
#define DPP_ROR(C, x) \
  __int_as_float(__builtin_amdgcn_update_dpp(0, __float_as_int(x), (0x120 | C), 0xF, 0xF, false))

__device__ __forceinline__ float rowsum16(float v) {
  v += DPP_ROR(8, v);
  v += DPP_ROR(4, v);
  v += DPP_ROR(2, v);
  v += DPP_ROR(1, v);
  return v;
}

// ---------------------------------------------------------------------------
__global__ void k_deg(const int* __restrict__ ei, int E, int Et, int* __restrict__ deg) {
  int e = blockIdx.x * blockDim.x + threadIdx.x;
  if (e >= Et) return;
  int d = (e < E) ? ei[E + e] : (e - E);  // dst only
  atomicAdd(&deg[d], 1);
}

// ---------------------------------------------------------------------------
// 3-phase parallel exclusive scan of deg[0..n) -> row_ptr[0..n], cursor copy.
// Phase A: per-block (1024 elems) sums.
__global__ __launch_bounds__(256) void k_scan_part(const int* __restrict__ deg,
                                                   int* __restrict__ bsum, int n) {
  __shared__ int sd[256];
  int t = threadIdx.x;
  int i = blockIdx.x * 1024 + t * 4;
  int s = 0;
  if (i + 4 <= n) {
    int4 d = *(const int4*)&deg[i];
    s = d.x + d.y + d.z + d.w;
  } else {
    for (int j = i; j < min(i + 4, n); ++j) s += deg[j];
  }
  sd[t] = s;
  __syncthreads();
  for (int off = 128; off; off >>= 1) {
    if (t < off) sd[t] += sd[t + off];
    __syncthreads();
  }
  if (t == 0) bsum[blockIdx.x] = sd[0];
}

// Phase B: 1 small block scans the <=64 partials (exclusive, in place).
__global__ __launch_bounds__(64) void k_scan_top(int* __restrict__ bsum, int nb) {
  __shared__ int s[64];
  int t = threadIdx.x;
  s[t] = (t < nb) ? bsum[t] : 0;
  __syncthreads();
  int acc = 0;
  for (int j = 0; j < t; ++j) acc += s[j];
  if (t < nb) bsum[t] = acc;
}

// Phase C: per-block local scan + block offset, int4 stores of both arrays.
__global__ __launch_bounds__(256) void k_scan_write(const int* __restrict__ deg,
                                                    const int* __restrict__ bsum,
                                                    int* __restrict__ row_ptr,
                                                    int* __restrict__ cursor, int n) {
  __shared__ int sd[256];
  int t = threadIdx.x;
  int i = blockIdx.x * 1024 + t * 4;
  int4 d = make_int4(0, 0, 0, 0);
  bool full = (i + 4 <= n);
  if (full) d = *(const int4*)&deg[i];
  else {
    if (i + 0 < n) d.x = deg[i + 0];
    if (i + 1 < n) d.y = deg[i + 1];
    if (i + 2 < n) d.z = deg[i + 2];
    if (i + 3 < n) d.w = deg[i + 3];
  }
  int s = d.x + d.y + d.z + d.w;
  sd[t] = s;
  __syncthreads();
  for (int off = 1; off < 256; off <<= 1) {  // Hillis-Steele inclusive
    int v = (t >= off) ? sd[t - off] : 0;
    __syncthreads();
    sd[t] += v;
    __syncthreads();
  }
  int ex = sd[t] - s + bsum[blockIdx.x];
  int4 r;
  r.x = ex;
  r.y = ex + d.x;
  r.z = r.y + d.y;
  r.w = r.z + d.z;
  if (full) {
    *(int4*)&row_ptr[i] = r;
    *(int4*)&cursor[i] = r;
    if (i + 4 == n) row_ptr[n] = r.w + d.w;
  } else if (i < n) {
    int run = ex;
    int vals[4] = {d.x, d.y, d.z, d.w};
    for (int j = 0; j < 4 && i + j < n; ++j) {
      row_ptr[i + j] = run;
      cursor[i + j] = run;
      run += vals[j];
    }
    if (i <= n && i + 4 > n) row_ptr[n] = run;
  }
}

__global__ void k_fill(const int* __restrict__ ei, int E, int Et,
                       int* __restrict__ cursor, int* __restrict__ csr_src) {
  int e = blockIdx.x * blockDim.x + threadIdx.x;
  if (e >= Et) return;
  int s, d;
  if (e < E) { s = ei[e]; d = ei[E + e]; }
  else       { s = e - E; d = s; }
  int slot = atomicAdd(&cursor[d], 1);  // cursor pre-loaded with row_ptr
  csr_src[slot] = s;
}

// ---------------------------------------------------------------------------
// out[n,128] = x[n,128] @ W[128,128], blockIdx.y selects Wl/Wr.
// 64x128 block tile, BK=16, 256 threads, 4x8 micro-tile.
__global__ __launch_bounds__(256) void k_gemm128(const float* __restrict__ x,
                                                 const float* __restrict__ Wl,
                                                 const float* __restrict__ Wr,
                                                 float* __restrict__ outl,
                                                 float* __restrict__ outr, int n) {
  __shared__ __align__(16) float xs[16][68];   // x tile transposed: [k][row]
  __shared__ __align__(16) float ws[16][132];  // W tile: [k][col]
  const float* W = blockIdx.y ? Wr : Wl;
  float* out = blockIdx.y ? outr : outl;
  int t = threadIdx.x;
  int tx = t & 15, ty = t >> 4;
  int r0 = blockIdx.x * 64;
  float acc[4][8] = {};

  int sr = t >> 2;           // x staging: row 0..63
  int sk = (t & 3) * 4;      // k-quad
  int wk = t >> 5;           // W staging: k row 0..7
  int wc = (t & 31) * 4;     // col quad

  for (int k0 = 0; k0 < 128; k0 += 16) {
    int gr = r0 + sr;
    float4 xv = make_float4(0.f, 0.f, 0.f, 0.f);
    if (gr < n) xv = *(const float4*)&x[(size_t)gr * 128 + k0 + sk];
    float4 wv0 = *(const float4*)&W[(size_t)(k0 + wk) * 128 + wc];
    float4 wv1 = *(const float4*)&W[(size_t)(k0 + wk + 8) * 128 + wc];
    __syncthreads();
    xs[sk + 0][sr] = xv.x;
    xs[sk + 1][sr] = xv.y;
    xs[sk + 2][sr] = xv.z;
    xs[sk + 3][sr] = xv.w;
    *(float4*)&ws[wk][wc] = wv0;
    *(float4*)&ws[wk + 8][wc] = wv1;
    __syncthreads();
#pragma unroll
    for (int k = 0; k < 16; ++k) {
      float4 av = *(const float4*)&xs[k][ty * 4];
      float4 b0 = *(const float4*)&ws[k][tx * 4];
      float4 b1 = *(const float4*)&ws[k][64 + tx * 4];
      float a[4] = {av.x, av.y, av.z, av.w};
      float b[8] = {b0.x, b0.y, b0.z, b0.w, b1.x, b1.y, b1.z, b1.w};
#pragma unroll
      for (int i = 0; i < 4; ++i)
#pragma unroll
        for (int j = 0; j < 8; ++j)
          acc[i][j] = fmaf(a[i], b[j], acc[i][j]);
    }
  }
#pragma unroll
  for (int i = 0; i < 4; ++i) {
    int gr = r0 + ty * 4 + i;
    if (gr < n) {
      *(float4*)&out[(size_t)gr * 128 + tx * 4] =
          make_float4(acc[i][0], acc[i][1], acc[i][2], acc[i][3]);
      *(float4*)&out[(size_t)gr * 128 + 64 + tx * 4] =
          make_float4(acc[i][4], acc[i][5], acc[i][6], acc[i][7]);
    }
  }
}

// ---------------------------------------------------------------------------
// fused layer-1 edge phase + layer-2 input projection.
// TWO nodes per wave: lanes 0-31 = node 2w, 32-63 = node 2w+1. Lane holds 4
// channels; 16-lane head groups = DPP rows. 4 edges/iter: clamp-free main
// loop to mindeg, clamped+masked tail to maxdeg.
__global__ __launch_bounds__(256) void k_fused1(const float* __restrict__ xl,
                                                const float* __restrict__ xr,
                                                const int* __restrict__ row_ptr,
                                                const int* __restrict__ csr_src,
                                                const float* __restrict__ att1,
                                                const float* __restrict__ b1,
                                                const float* __restrict__ W2l,
                                                const float* __restrict__ W2r,
                                                float* __restrict__ xl2,
                                                float* __restrict__ xr2, int n) {
  int wid  = (blockIdx.x * 256 + threadIdx.x) >> 6;
  int lane = threadIdx.x & 63;
  int sub  = lane & 31;
  int node = min(wid * 2 + (lane >> 5), n - 1);  // dup of last node is benign
  int ch = sub * 4;
  const char* xlb = (const char*)xl;
  unsigned chb = (unsigned)ch * 4u;
  float4 xrv = *(const float4*)&xr[(size_t)node * 128 + ch];
  float4 atv = *(const float4*)&att1[ch];
  atv.x *= LOG2E; atv.y *= LOG2E; atv.z *= LOG2E; atv.w *= LOG2E;
  int s0 = row_ptr[node];
  int deg = row_ptr[node + 1] - s0;  // >=1 (self-loop)
  int odeg = __shfl_xor(deg, 32);
  int mindeg = min(deg, odeg);  // wave-uniform
  int maxdeg = max(deg, odeg);  // wave-uniform
  const int* sp = csr_src + s0;

  float m = -1e30f, l = 0.f;
  float4 acc = make_float4(0.f, 0.f, 0.f, 0.f);

  float t0, t1, t2, t3;
#define LOGIT(p, v)                                                     \
    t0 = v.x + xrv.x; t0 = fmaxf(t0, 0.2f * t0);                        \
    t1 = v.y + xrv.y; t1 = fmaxf(t1, 0.2f * t1);                        \
    t2 = v.z + xrv.z; t2 = fmaxf(t2, 0.2f * t2);                        \
    t3 = v.w + xrv.w; t3 = fmaxf(t3, 0.2f * t3);                        \
    p = fmaf(t3, atv.w, fmaf(t2, atv.z, fmaf(t1, atv.y, t0 * atv.x)));

#define BODY(CLAMPED)                                                   \
  {                                                                     \
    int sA, sB, sC, sD;                                                 \
    if (CLAMPED) {                                                      \
      int dm1 = deg - 1;                                                \
      sA = sp[min(e + 0, dm1)];                                         \
      sB = sp[min(e + 1, dm1)];                                         \
      sC = sp[min(e + 2, dm1)];                                         \
      sD = sp[min(e + 3, dm1)];                                         \
    } else {                                                            \
      sA = sp[e + 0]; sB = sp[e + 1]; sC = sp[e + 2]; sD = sp[e + 3];   \
    }                                                                   \
    float4 xa = *(const float4*)(xlb + (((unsigned)sA << 9) + chb));    \
    float4 xb = *(const float4*)(xlb + (((unsigned)sB << 9) + chb));    \
    float4 xc = *(const float4*)(xlb + (((unsigned)sC << 9) + chb));    \
    float4 xd = *(const float4*)(xlb + (((unsigned)sD << 9) + chb));    \
    float pa, pb, pc, pd;                                               \
    LOGIT(pa, xa) LOGIT(pb, xb) LOGIT(pc, xc) LOGIT(pd, xd)             \
    pa = rowsum16(pa);                                                  \
    pb = rowsum16(pb);                                                  \
    pc = rowsum16(pc);                                                  \
    pd = rowsum16(pd);                                                  \
    if (CLAMPED) {                                                      \
      pa = (e + 0 < deg) ? pa : -1e30f;                                 \
      pb = (e + 1 < deg) ? pb : -1e30f;                                 \
      pc = (e + 2 < deg) ? pc : -1e30f;                                 \
      pd = (e + 3 < deg) ? pd : -1e30f;                                 \
    }                                                                   \
    float mn = fmaxf(m, fmaxf(fmaxf(pa, pb), fmaxf(pc, pd)));           \
    float sc = exp2f(m - mn);                                           \
    float wa = exp2f(pa - mn);                                          \
    float wb = exp2f(pb - mn);                                          \
    float wc = exp2f(pc - mn);                                          \
    float wd = exp2f(pd - mn);                                          \
    acc.x = fmaf(wd, xd.x, fmaf(wc, xc.x, fmaf(wb, xb.x, fmaf(wa, xa.x, acc.x * sc)))); \
    acc.y = fmaf(wd, xd.y, fmaf(wc, xc.y, fmaf(wb, xb.y, fmaf(wa, xa.y, acc.y * sc)))); \
    acc.z = fmaf(wd, xd.z, fmaf(wc, xc.z, fmaf(wb, xb.z, fmaf(wa, xa.z, acc.z * sc)))); \
    acc.w = fmaf(wd, xd.w, fmaf(wc, xc.w, fmaf(wb, xb.w, fmaf(wa, xa.w, acc.w * sc)))); \
    l = fmaf(l, sc, wa + wb + wc + wd);                                 \
    m = mn;                                                             \
  }

  int e = 0;
  for (; e + 4 <= mindeg; e += 4) BODY(false)
  for (; e < maxdeg; e += 4) BODY(true)
#undef BODY
#undef LOGIT

  float inv = 1.f / (l + 1e-16f);
  float4 b1v = *(const float4*)&b1[ch];
  float4 h;
  h.x = acc.x * inv + b1v.x; h.x = h.x > 0.f ? h.x : expm1f(h.x);
  h.y = acc.y * inv + b1v.y; h.y = h.y > 0.f ? h.y : expm1f(h.y);
  h.z = acc.z * inv + b1v.z; h.z = h.z > 0.f ? h.z : expm1f(h.z);
  h.w = acc.w * inv + b1v.w; h.w = h.w > 0.f ? h.w : expm1f(h.w);

  float4 u0 = *(const float4*)&W2l[ch * 3 + 0];
  float4 u1 = *(const float4*)&W2l[ch * 3 + 4];
  float4 u2 = *(const float4*)&W2l[ch * 3 + 8];
  float al0 = fmaf(h.w, u2.y, fmaf(h.z, u1.z, fmaf(h.y, u0.w, h.x * u0.x)));
  float al1 = fmaf(h.w, u2.z, fmaf(h.z, u1.w, fmaf(h.y, u1.x, h.x * u0.y)));
  float al2 = fmaf(h.w, u2.w, fmaf(h.z, u2.x, fmaf(h.y, u1.y, h.x * u0.z)));
  float4 v0 = *(const float4*)&W2r[ch * 3 + 0];
  float4 v1 = *(const float4*)&W2r[ch * 3 + 4];
  float4 v2 = *(const float4*)&W2r[ch * 3 + 8];
  float ar0 = fmaf(h.w, v2.y, fmaf(h.z, v1.z, fmaf(h.y, v0.w, h.x * v0.x)));
  float ar1 = fmaf(h.w, v2.z, fmaf(h.z, v1.w, fmaf(h.y, v1.x, h.x * v0.y)));
  float ar2 = fmaf(h.w, v2.w, fmaf(h.z, v2.x, fmaf(h.y, v1.y, h.x * v0.z)));
#pragma unroll
  for (int off = 1; off < 32; off <<= 1) {
    al0 += __shfl_xor(al0, off); al1 += __shfl_xor(al1, off);
    al2 += __shfl_xor(al2, off); ar0 += __shfl_xor(ar0, off);
    ar1 += __shfl_xor(ar1, off); ar2 += __shfl_xor(ar2, off);
  }
  if (sub == 0 && wid * 2 + (lane >> 5) < n) {
    *(float4*)&xl2[node * 4] = make_float4(al0, al1, al2, 0.f);
    *(float4*)&xr2[node * 4] = make_float4(ar0, ar1, ar2, 0.f);
  }
}

// ---------------------------------------------------------------------------
// fused layer-2 edge phase + mean-pool. 16 lanes per node (= one DPP row);
// per-lane online softmax (exp2 domain) over a 16-stride slice, DPP rotate
// merge of (m,l,acc3) states. Pool pre-reduced in LDS.
__global__ __launch_bounds__(256) void k_fused2(const float* __restrict__ xl2,
                                                const float* __restrict__ xr2,
                                                const int* __restrict__ row_ptr,
                                                const int* __restrict__ csr_src,
                                                const float* __restrict__ att2,
                                                const float* __restrict__ b2,
                                                const int* __restrict__ batch,
                                                float* __restrict__ gsum,
                                                float* __restrict__ gcnt, int n) {
  __shared__ float ls[NGRAPH * 3];
  __shared__ float lc[NGRAPH];
  int t = threadIdx.x;
  for (int i = t; i < NGRAPH * 3; i += 256) ls[i] = 0.f;
  for (int i = t; i < NGRAPH; i += 256) lc[i] = 0.f;
  __syncthreads();

  int node = (blockIdx.x * 256 + t) >> 4;  // 16 nodes per block
  int lane = t & 15;
  if (node < n) {
    float4 xrv = *(const float4*)&xr2[node * 4];
    float c0 = att2[0] * LOG2E, c1 = att2[1] * LOG2E, c2 = att2[2] * LOG2E;
    int s0 = row_ptr[node], s1 = row_ptr[node + 1];
    float m = -1e30f, l = 0.f, a0 = 0.f, a1 = 0.f, a2 = 0.f;
    for (int slot = s0 + lane; slot < s1; slot += 16) {
      int s = csr_src[slot];
      float4 xlv = *(const float4*)&xl2[s * 4];
      float t0 = xlv.x + xrv.x; t0 = fmaxf(t0, 0.2f * t0);
      float t1 = xlv.y + xrv.y; t1 = fmaxf(t1, 0.2f * t1);
      float t2 = xlv.z + xrv.z; t2 = fmaxf(t2, 0.2f * t2);
      float p = fmaf(t2, c2, fmaf(t1, c1, t0 * c0));
      float mn = fmaxf(m, p);
      float sc = exp2f(m - mn);
      float w  = exp2f(p - mn);
      a0 = a0 * sc + w * xlv.x;
      a1 = a1 * sc + w * xlv.y;
      a2 = a2 * sc + w * xlv.z;
      l = l * sc + w;
      m = mn;
    }
#define MERGE(C)                                                        \
    {                                                                   \
      float m2 = DPP_ROR(C, m);                                         \
      float l2 = DPP_ROR(C, l);                                         \
      float b0 = DPP_ROR(C, a0);                                        \
      float b1v = DPP_ROR(C, a1);                                       \
      float b2v = DPP_ROR(C, a2);                                       \
      float mn = fmaxf(m, m2);                                          \
      float sA = exp2f(m - mn);                                         \
      float sB = exp2f(m2 - mn);                                        \
      a0 = a0 * sA + b0 * sB;                                           \
      a1 = a1 * sA + b1v * sB;                                          \
      a2 = a2 * sA + b2v * sB;                                          \
      l = l * sA + l2 * sB;                                             \
      m = mn;                                                           \
    }
    MERGE(8) MERGE(4) MERGE(2) MERGE(1)
#undef MERGE
    if (lane == 0) {
      float inv = 1.f / (l + 1e-16f);
      float o0 = a0 * inv + b2[0];
      float o1 = a1 * inv + b2[1];
      float o2 = a2 * inv + b2[2];
      int b = batch[node];
      atomicAdd(&ls[b * 3 + 0], o0);
      atomicAdd(&ls[b * 3 + 1], o1);
      atomicAdd(&ls[b * 3 + 2], o2);
      atomicAdd(&lc[b], 1.f);
    }
  }
  __syncthreads();
  for (int i = t; i < NGRAPH * 3; i += 256)
    if (ls[i] != 0.f) atomicAdd(&gsum[i], ls[i]);
  for (int i = t; i < NGRAPH; i += 256)
    if (lc[i] != 0.f) atomicAdd(&gcnt[i], lc[i]);
}

// 1 block, 64 threads: per-graph mean + 2-layer MLP
__global__ __launch_bounds__(64) void k_mlp(const float* __restrict__ gsum,
                                            const float* __restrict__ gcnt,
                                            const float* __restrict__ Wr1,
                                            const float* __restrict__ br1,
                                            const float* __restrict__ Wr2,
                                            const float* __restrict__ br2,
                                            float* __restrict__ out) {
  int t = threadIdx.x;
  if (t >= NGRAPH) return;
  float cnt = fmaxf(gcnt[t], 1.f);
  float g0 = gsum[t * 3 + 0] / cnt;
  float g1 = gsum[t * 3 + 1] / cnt;
  float g2 = gsum[t * 3 + 2] / cnt;
  float o0 = br2[0], o1 = br2[1], o2 = br2[2];
  for (int j = 0; j < 64; ++j) {
    float hj = g0 * Wr1[j] + g1 * Wr1[64 + j] + g2 * Wr1[128 + j] + br1[j];
    hj = fmaxf(hj, 0.f);
    o0 = fmaf(hj, Wr2[j * 3 + 0], o0);
    o1 = fmaf(hj, Wr2[j * 3 + 1], o1);
    o2 = fmaf(hj, Wr2[j * 3 + 2], o2);
  }
  out[t * 3 + 0] = o0;
  out[t * 3 + 1] = o1;
  out[t * 3 + 2] = o2;
}

// ---------------------------------------------------------------------------
extern "C" void kernel_launch(void* const* d_in, const int* in_sizes, int n_in,
                              void* d_out, int out_size, void* d_ws, size_t ws_size,
                              hipStream_t stream) {
  const float* x    = (const float*)d_in[0];
  const int*   ei   = (const int*)d_in[1];
  const int*   batch= (const int*)d_in[2];
  const float* W1l  = (const float*)d_in[3];
  const float* W1r  = (const float*)d_in[4];
  const float* att1 = (const float*)d_in[5];
  const float* b1   = (const float*)d_in[6];
  const float* W2l  = (const float*)d_in[7];
  const float* W2r  = (const float*)d_in[8];
  const float* att2 = (const float*)d_in[9];
  const float* b2   = (const float*)d_in[10];
  const float* Wr1  = (const float*)d_in[11];
  const float* br1  = (const float*)d_in[12];
  const float* Wr2  = (const float*)d_in[13];
  const float* br2  = (const float*)d_in[14];
  float* out = (float*)d_out;

  const int N  = in_sizes[0] / 128;
  const int E  = in_sizes[1] / 2;
  const int Et = E + N;
  const int NB = (N + 1023) / 1024;  // scan blocks (<=64)

  char* p = (char*)d_ws;
  auto alloc = [&](size_t bytes) -> char* {
    char* r = p;
    p += (bytes + 255) & ~(size_t)255;
    return r;
  };
  float*    xl1    = (float*)alloc((size_t)N * 128 * 4);
  float*    xr1    = (float*)alloc((size_t)N * 128 * 4);
  int*      row_ptr= (int*)alloc((size_t)(N + 1) * 4);
  int*      csr_src= (int*)alloc((size_t)Et * 4);
  int*      cursor = (int*)alloc((size_t)N * 4);
  int*      bsum   = (int*)alloc(64 * 4);
  // zero-init group (one memset): deg | gsum | gcnt
  char*     z0     = p;
  int*      deg    = (int*)alloc((size_t)N * 4);
  float*    gsum   = (float*)alloc(NGRAPH * 3 * 4);
  float*    gcnt   = (float*)alloc(NGRAPH * 4);
  size_t    zbytes = (size_t)(p - z0);
  float*    xl2    = (float*)alloc((size_t)N * 4 * 4);
  float*    xr2    = (float*)alloc((size_t)N * 4 * 4);

  hipMemsetAsync(z0, 0, zbytes, stream);
  hipLaunchKernelGGL(k_deg, dim3((Et + 255) / 256), dim3(256), 0, stream, ei, E, Et, deg);
  hipLaunchKernelGGL(k_scan_part, dim3(NB), dim3(256), 0, stream, deg, bsum, N);
  hipLaunchKernelGGL(k_scan_top, dim3(1), dim3(64), 0, stream, bsum, NB);
  hipLaunchKernelGGL(k_scan_write, dim3(NB), dim3(256), 0, stream,
                     deg, bsum, row_ptr, cursor, N);
  hipLaunchKernelGGL(k_fill, dim3((Et + 255) / 256), dim3(256), 0, stream,
                     ei, E, Et, cursor, csr_src);
  hipLaunchKernelGGL(k_gemm128, dim3((N + 63) / 64, 2), dim3(256), 0, stream,
                     x, W1l, W1r, xl1, xr1, N);
  int waves1 = (N + 1) / 2;
  hipLaunchKernelGGL(k_fused1, dim3((waves1 * 64 + 255) / 256), dim3(256), 0, stream,
                     xl1, xr1, row_ptr, csr_src, att1, b1, W2l, W2r, xl2, xr2, N);
  hipLaunchKernelGGL(k_fused2, dim3((N * 16 + 255) / 256), dim3(256), 0, stream,
                     xl2, xr2, row_ptr, csr_src, att2, b2, batch, gsum, gcnt, N);
  hipLaunchKernelGGL(k_mlp, dim3(1), dim3(64), 0, stream,
                     gsum, gcnt, Wr1, br1, Wr2, br2, out);
}

// Round 12
// 325.728 us; speedup vs baseline: 1.7776x; 1.0096x over previous
//
#include <hip/hip_runtime.h>

// ---------------------------------------------------------------------------
// GATv2 (2 layers) + mean-pool + MLP for MI355X.
// N=50000 nodes, E=800000 edges (+N self loops), IN=128, HID=64, HEADS=2,
// OUT=3, 64 graphs. Output: [64,3] float32.
// R1: k_agg2 pool atomic storm fixed (LDS pre-reduction). 1128 -> 803 us.
// R2: CSR + per-node online softmax; edge phases fused.   803 -> 515 us.
// R3: fused1 2-edge ILP + reg src cache + W2-proj fused.   515 -> 394 us.
// R4: fused1 2 nodes/wave + 4-edge ILP + batched softmax.  394 -> 368 us.
// R5: gemm 128x128 reg-blocked (LDS 72KB->16KB).            368 -> 343 us.
// R6: DPP rotate-reduce + exp2 domain; gemm 64x128/4x8.     343 -> 337 us.
// R7: 8-edge unroll flat (VGPR 52, occ 35 cancels savings). 337 -> 335 us.
// R8-R10: degree-sort detour REGRESSED (atomic storms + single-block scan
//     exposed at 100us). R11: 3-phase parallel scan.        422 -> 329 us.
// R12: fused1 proven fabric-BW-bound (197MB @ 3.2TB/s = its 64us, invariant
//     across VALU/occupancy changes R6-R11). xl1 message table -> bf16:
//     gather 512->256B/edge, table 25.6->12.8MB (L2 hit up). xr1/logits/acc
//     stay fp32. Est. output err ~1e-7 vs 3.8e-6 threshold.
// ---------------------------------------------------------------------------

#define NGRAPH 64
#define LOG2E 1.4426950408889634f

// v_mov_dpp row_ror:k (16-lane rows). Valid reduce permutation for
// commutative ops; leaves every lane of the row with the full result.
#define DPP_ROR(C, x) \
  __int_as_float(__builtin_amdgcn_update_dpp(0, __float_as_int(x), (0x120 | C), 0xF, 0xF, false))

__device__ __forceinline__ float rowsum16(float v) {
  v += DPP_ROR(8, v);
  v += DPP_ROR(4, v);
  v += DPP_ROR(2, v);
  v += DPP_ROR(1, v);
  return v;
}

__device__ __forceinline__ unsigned bf16rne(float f) {
  unsigned u = __float_as_uint(f);
  return (u + 0x7FFFu + ((u >> 16) & 1u)) >> 16;
}

// ---------------------------------------------------------------------------
__global__ void k_deg(const int* __restrict__ ei, int E, int Et, int* __restrict__ deg) {
  int e = blockIdx.x * blockDim.x + threadIdx.x;
  if (e >= Et) return;
  int d = (e < E) ? ei[E + e] : (e - E);  // dst only
  atomicAdd(&deg[d], 1);
}

// ---------------------------------------------------------------------------
// 3-phase parallel exclusive scan of deg[0..n) -> row_ptr[0..n], cursor copy.
__global__ __launch_bounds__(256) void k_scan_part(const int* __restrict__ deg,
                                                   int* __restrict__ bsum, int n) {
  __shared__ int sd[256];
  int t = threadIdx.x;
  int i = blockIdx.x * 1024 + t * 4;
  int s = 0;
  if (i + 4 <= n) {
    int4 d = *(const int4*)&deg[i];
    s = d.x + d.y + d.z + d.w;
  } else {
    for (int j = i; j < min(i + 4, n); ++j) s += deg[j];
  }
  sd[t] = s;
  __syncthreads();
  for (int off = 128; off; off >>= 1) {
    if (t < off) sd[t] += sd[t + off];
    __syncthreads();
  }
  if (t == 0) bsum[blockIdx.x] = sd[0];
}

__global__ __launch_bounds__(64) void k_scan_top(int* __restrict__ bsum, int nb) {
  __shared__ int s[64];
  int t = threadIdx.x;
  s[t] = (t < nb) ? bsum[t] : 0;
  __syncthreads();
  int acc = 0;
  for (int j = 0; j < t; ++j) acc += s[j];
  if (t < nb) bsum[t] = acc;
}

__global__ __launch_bounds__(256) void k_scan_write(const int* __restrict__ deg,
                                                    const int* __restrict__ bsum,
                                                    int* __restrict__ row_ptr,
                                                    int* __restrict__ cursor, int n) {
  __shared__ int sd[256];
  int t = threadIdx.x;
  int i = blockIdx.x * 1024 + t * 4;
  int4 d = make_int4(0, 0, 0, 0);
  bool full = (i + 4 <= n);
  if (full) d = *(const int4*)&deg[i];
  else {
    if (i + 0 < n) d.x = deg[i + 0];
    if (i + 1 < n) d.y = deg[i + 1];
    if (i + 2 < n) d.z = deg[i + 2];
    if (i + 3 < n) d.w = deg[i + 3];
  }
  int s = d.x + d.y + d.z + d.w;
  sd[t] = s;
  __syncthreads();
  for (int off = 1; off < 256; off <<= 1) {  // Hillis-Steele inclusive
    int v = (t >= off) ? sd[t - off] : 0;
    __syncthreads();
    sd[t] += v;
    __syncthreads();
  }
  int ex = sd[t] - s + bsum[blockIdx.x];
  int4 r;
  r.x = ex;
  r.y = ex + d.x;
  r.z = r.y + d.y;
  r.w = r.z + d.z;
  if (full) {
    *(int4*)&row_ptr[i] = r;
    *(int4*)&cursor[i] = r;
    if (i + 4 == n) row_ptr[n] = r.w + d.w;
  } else if (i < n) {
    int run = ex;
    int vals[4] = {d.x, d.y, d.z, d.w};
    for (int j = 0; j < 4 && i + j < n; ++j) {
      row_ptr[i + j] = run;
      cursor[i + j] = run;
      run += vals[j];
    }
    if (i <= n && i + 4 > n) row_ptr[n] = run;
  }
}

__global__ void k_fill(const int* __restrict__ ei, int E, int Et,
                       int* __restrict__ cursor, int* __restrict__ csr_src) {
  int e = blockIdx.x * blockDim.x + threadIdx.x;
  if (e >= Et) return;
  int s, d;
  if (e < E) { s = ei[e]; d = ei[E + e]; }
  else       { s = e - E; d = s; }
  int slot = atomicAdd(&cursor[d], 1);  // cursor pre-loaded with row_ptr
  csr_src[slot] = s;
}

// ---------------------------------------------------------------------------
// blockIdx.y==0: xl1 = x@W1l stored BF16 (message table, gather-bound user).
// blockIdx.y==1: xr1 = x@W1r stored FP32.
// 64x128 block tile, BK=16, 256 threads, 4x8 micro-tile.
__global__ __launch_bounds__(256) void k_gemm128(const float* __restrict__ x,
                                                 const float* __restrict__ Wl,
                                                 const float* __restrict__ Wr,
                                                 unsigned short* __restrict__ outl,
                                                 float* __restrict__ outr, int n) {
  __shared__ __align__(16) float xs[16][68];   // x tile transposed: [k][row]
  __shared__ __align__(16) float ws[16][132];  // W tile: [k][col]
  const float* W = blockIdx.y ? Wr : Wl;
  int t = threadIdx.x;
  int tx = t & 15, ty = t >> 4;
  int r0 = blockIdx.x * 64;
  float acc[4][8] = {};

  int sr = t >> 2;           // x staging: row 0..63
  int sk = (t & 3) * 4;      // k-quad
  int wk = t >> 5;           // W staging: k row 0..7
  int wc = (t & 31) * 4;     // col quad

  for (int k0 = 0; k0 < 128; k0 += 16) {
    int gr = r0 + sr;
    float4 xv = make_float4(0.f, 0.f, 0.f, 0.f);
    if (gr < n) xv = *(const float4*)&x[(size_t)gr * 128 + k0 + sk];
    float4 wv0 = *(const float4*)&W[(size_t)(k0 + wk) * 128 + wc];
    float4 wv1 = *(const float4*)&W[(size_t)(k0 + wk + 8) * 128 + wc];
    __syncthreads();
    xs[sk + 0][sr] = xv.x;
    xs[sk + 1][sr] = xv.y;
    xs[sk + 2][sr] = xv.z;
    xs[sk + 3][sr] = xv.w;
    *(float4*)&ws[wk][wc] = wv0;
    *(float4*)&ws[wk + 8][wc] = wv1;
    __syncthreads();
#pragma unroll
    for (int k = 0; k < 16; ++k) {
      float4 av = *(const float4*)&xs[k][ty * 4];
      float4 b0 = *(const float4*)&ws[k][tx * 4];
      float4 b1 = *(const float4*)&ws[k][64 + tx * 4];
      float a[4] = {av.x, av.y, av.z, av.w};
      float b[8] = {b0.x, b0.y, b0.z, b0.w, b1.x, b1.y, b1.z, b1.w};
#pragma unroll
      for (int i = 0; i < 4; ++i)
#pragma unroll
        for (int j = 0; j < 8; ++j)
          acc[i][j] = fmaf(a[i], b[j], acc[i][j]);
    }
  }
  if (blockIdx.y == 0) {
#pragma unroll
    for (int i = 0; i < 4; ++i) {
      int gr = r0 + ty * 4 + i;
      if (gr < n) {
        uint2 p0, p1;
        p0.x = bf16rne(acc[i][0]) | (bf16rne(acc[i][1]) << 16);
        p0.y = bf16rne(acc[i][2]) | (bf16rne(acc[i][3]) << 16);
        p1.x = bf16rne(acc[i][4]) | (bf16rne(acc[i][5]) << 16);
        p1.y = bf16rne(acc[i][6]) | (bf16rne(acc[i][7]) << 16);
        *(uint2*)&outl[(size_t)gr * 128 + tx * 4] = p0;
        *(uint2*)&outl[(size_t)gr * 128 + 64 + tx * 4] = p1;
      }
    }
  } else {
#pragma unroll
    for (int i = 0; i < 4; ++i) {
      int gr = r0 + ty * 4 + i;
      if (gr < n) {
        *(float4*)&outr[(size_t)gr * 128 + tx * 4] =
            make_float4(acc[i][0], acc[i][1], acc[i][2], acc[i][3]);
        *(float4*)&outr[(size_t)gr * 128 + 64 + tx * 4] =
            make_float4(acc[i][4], acc[i][5], acc[i][6], acc[i][7]);
      }
    }
  }
}

// ---------------------------------------------------------------------------
// fused layer-1 edge phase + layer-2 input projection.
// TWO nodes per wave: lanes 0-31 = node 2w, 32-63 = node 2w+1. Lane holds 4
// channels; 16-lane head groups = DPP rows. 4 edges/iter: clamp-free main
// loop to mindeg, clamped+masked tail to maxdeg. R12: xl gathered as BF16x4
// (uint2, 8B/lane = 256B/row) and unpacked with shift/mask; acc fp32.
__global__ __launch_bounds__(256) void k_fused1(const unsigned short* __restrict__ xl,
                                                const float* __restrict__ xr,
                                                const int* __restrict__ row_ptr,
                                                const int* __restrict__ csr_src,
                                                const float* __restrict__ att1,
                                                const float* __restrict__ b1,
                                                const float* __restrict__ W2l,
                                                const float* __restrict__ W2r,
                                                float* __restrict__ xl2,
                                                float* __restrict__ xr2, int n) {
  int wid  = (blockIdx.x * 256 + threadIdx.x) >> 6;
  int lane = threadIdx.x & 63;
  int sub  = lane & 31;
  int node = min(wid * 2 + (lane >> 5), n - 1);  // dup of last node is benign
  int ch = sub * 4;
  const char* xlb = (const char*)xl;
  unsigned chb = (unsigned)sub * 8u;  // byte offset within 256B bf16 row
  float4 xrv = *(const float4*)&xr[(size_t)node * 128 + ch];
  float4 atv = *(const float4*)&att1[ch];
  atv.x *= LOG2E; atv.y *= LOG2E; atv.z *= LOG2E; atv.w *= LOG2E;
  int s0 = row_ptr[node];
  int deg = row_ptr[node + 1] - s0;  // >=1 (self-loop)
  int odeg = __shfl_xor(deg, 32);
  int mindeg = min(deg, odeg);  // wave-uniform
  int maxdeg = max(deg, odeg);  // wave-uniform
  const int* sp = csr_src + s0;

  float m = -1e30f, l = 0.f;
  float4 acc = make_float4(0.f, 0.f, 0.f, 0.f);

  float t0, t1, t2, t3;
#define UNPACK(dst, q)                                                  \
    dst.x = __uint_as_float(q.x << 16);                                 \
    dst.y = __uint_as_float(q.x & 0xFFFF0000u);                         \
    dst.z = __uint_as_float(q.y << 16);                                 \
    dst.w = __uint_as_float(q.y & 0xFFFF0000u);
#define LOGIT(p, v)                                                     \
    t0 = v.x + xrv.x; t0 = fmaxf(t0, 0.2f * t0);                        \
    t1 = v.y + xrv.y; t1 = fmaxf(t1, 0.2f * t1);                        \
    t2 = v.z + xrv.z; t2 = fmaxf(t2, 0.2f * t2);                        \
    t3 = v.w + xrv.w; t3 = fmaxf(t3, 0.2f * t3);                        \
    p = fmaf(t3, atv.w, fmaf(t2, atv.z, fmaf(t1, atv.y, t0 * atv.x)));

#define BODY(CLAMPED)                                                   \
  {                                                                     \
    int sA, sB, sC, sD;                                                 \
    if (CLAMPED) {                                                      \
      int dm1 = deg - 1;                                                \
      sA = sp[min(e + 0, dm1)];                                         \
      sB = sp[min(e + 1, dm1)];                                         \
      sC = sp[min(e + 2, dm1)];                                         \
      sD = sp[min(e + 3, dm1)];                                         \
    } else {                                                            \
      sA = sp[e + 0]; sB = sp[e + 1]; sC = sp[e + 2]; sD = sp[e + 3];   \
    }                                                                   \
    uint2 qa = *(const uint2*)(xlb + (((unsigned)sA << 8) + chb));      \
    uint2 qb = *(const uint2*)(xlb + (((unsigned)sB << 8) + chb));      \
    uint2 qc = *(const uint2*)(xlb + (((unsigned)sC << 8) + chb));      \
    uint2 qd = *(const uint2*)(xlb + (((unsigned)sD << 8) + chb));      \
    float4 xa, xb, xc, xd;                                              \
    UNPACK(xa, qa) UNPACK(xb, qb) UNPACK(xc, qc) UNPACK(xd, qd)         \
    float pa, pb, pc, pd;                                               \
    LOGIT(pa, xa) LOGIT(pb, xb) LOGIT(pc, xc) LOGIT(pd, xd)             \
    pa = rowsum16(pa);                                                  \
    pb = rowsum16(pb);                                                  \
    pc = rowsum16(pc);                                                  \
    pd = rowsum16(pd);                                                  \
    if (CLAMPED) {                                                      \
      pa = (e + 0 < deg) ? pa : -1e30f;                                 \
      pb = (e + 1 < deg) ? pb : -1e30f;                                 \
      pc = (e + 2 < deg) ? pc : -1e30f;                                 \
      pd = (e + 3 < deg) ? pd : -1e30f;                                 \
    }                                                                   \
    float mn = fmaxf(m, fmaxf(fmaxf(pa, pb), fmaxf(pc, pd)));           \
    float sc = exp2f(m - mn);                                           \
    float wa = exp2f(pa - mn);                                          \
    float wb = exp2f(pb - mn);                                          \
    float wc = exp2f(pc - mn);                                          \
    float wd = exp2f(pd - mn);                                          \
    acc.x = fmaf(wd, xd.x, fmaf(wc, xc.x, fmaf(wb, xb.x, fmaf(wa, xa.x, acc.x * sc)))); \
    acc.y = fmaf(wd, xd.y, fmaf(wc, xc.y, fmaf(wb, xb.y, fmaf(wa, xa.y, acc.y * sc)))); \
    acc.z = fmaf(wd, xd.z, fmaf(wc, xc.z, fmaf(wb, xb.z, fmaf(wa, xa.z, acc.z * sc)))); \
    acc.w = fmaf(wd, xd.w, fmaf(wc, xc.w, fmaf(wb, xb.w, fmaf(wa, xa.w, acc.w * sc)))); \
    l = fmaf(l, sc, wa + wb + wc + wd);                                 \
    m = mn;                                                             \
  }

  int e = 0;
  for (; e + 4 <= mindeg; e += 4) BODY(false)
  for (; e < maxdeg; e += 4) BODY(true)
#undef BODY
#undef LOGIT
#undef UNPACK

  float inv = 1.f / (l + 1e-16f);
  float4 b1v = *(const float4*)&b1[ch];
  float4 h;
  h.x = acc.x * inv + b1v.x; h.x = h.x > 0.f ? h.x : expm1f(h.x);
  h.y = acc.y * inv + b1v.y; h.y = h.y > 0.f ? h.y : expm1f(h.y);
  h.z = acc.z * inv + b1v.z; h.z = h.z > 0.f ? h.z : expm1f(h.z);
  h.w = acc.w * inv + b1v.w; h.w = h.w > 0.f ? h.w : expm1f(h.w);

  float4 u0 = *(const float4*)&W2l[ch * 3 + 0];
  float4 u1 = *(const float4*)&W2l[ch * 3 + 4];
  float4 u2 = *(const float4*)&W2l[ch * 3 + 8];
  float al0 = fmaf(h.w, u2.y, fmaf(h.z, u1.z, fmaf(h.y, u0.w, h.x * u0.x)));
  float al1 = fmaf(h.w, u2.z, fmaf(h.z, u1.w, fmaf(h.y, u1.x, h.x * u0.y)));
  float al2 = fmaf(h.w, u2.w, fmaf(h.z, u2.x, fmaf(h.y, u1.y, h.x * u0.z)));
  float4 v0 = *(const float4*)&W2r[ch * 3 + 0];
  float4 v1 = *(const float4*)&W2r[ch * 3 + 4];
  float4 v2 = *(const float4*)&W2r[ch * 3 + 8];
  float ar0 = fmaf(h.w, v2.y, fmaf(h.z, v1.z, fmaf(h.y, v0.w, h.x * v0.x)));
  float ar1 = fmaf(h.w, v2.z, fmaf(h.z, v1.w, fmaf(h.y, v1.x, h.x * v0.y)));
  float ar2 = fmaf(h.w, v2.w, fmaf(h.z, v2.x, fmaf(h.y, v1.y, h.x * v0.z)));
#pragma unroll
  for (int off = 1; off < 32; off <<= 1) {
    al0 += __shfl_xor(al0, off); al1 += __shfl_xor(al1, off);
    al2 += __shfl_xor(al2, off); ar0 += __shfl_xor(ar0, off);
    ar1 += __shfl_xor(ar1, off); ar2 += __shfl_xor(ar2, off);
  }
  if (sub == 0 && wid * 2 + (lane >> 5) < n) {
    *(float4*)&xl2[node * 4] = make_float4(al0, al1, al2, 0.f);
    *(float4*)&xr2[node * 4] = make_float4(ar0, ar1, ar2, 0.f);
  }
}

// ---------------------------------------------------------------------------
// fused layer-2 edge phase + mean-pool. 16 lanes per node (= one DPP row);
// per-lane online softmax (exp2 domain) over a 16-stride slice, DPP rotate
// merge of (m,l,acc3) states. Pool pre-reduced in LDS.
__global__ __launch_bounds__(256) void k_fused2(const float* __restrict__ xl2,
                                                const float* __restrict__ xr2,
                                                const int* __restrict__ row_ptr,
                                                const int* __restrict__ csr_src,
                                                const float* __restrict__ att2,
                                                const float* __restrict__ b2,
                                                const int* __restrict__ batch,
                                                float* __restrict__ gsum,
                                                float* __restrict__ gcnt, int n) {
  __shared__ float ls[NGRAPH * 3];
  __shared__ float lc[NGRAPH];
  int t = threadIdx.x;
  for (int i = t; i < NGRAPH * 3; i += 256) ls[i] = 0.f;
  for (int i = t; i < NGRAPH; i += 256) lc[i] = 0.f;
  __syncthreads();

  int node = (blockIdx.x * 256 + t) >> 4;  // 16 nodes per block
  int lane = t & 15;
  if (node < n) {
    float4 xrv = *(const float4*)&xr2[node * 4];
    float c0 = att2[0] * LOG2E, c1 = att2[1] * LOG2E, c2 = att2[2] * LOG2E;
    int s0 = row_ptr[node], s1 = row_ptr[node + 1];
    float m = -1e30f, l = 0.f, a0 = 0.f, a1 = 0.f, a2 = 0.f;
    for (int slot = s0 + lane; slot < s1; slot += 16) {
      int s = csr_src[slot];
      float4 xlv = *(const float4*)&xl2[s * 4];
      float t0 = xlv.x + xrv.x; t0 = fmaxf(t0, 0.2f * t0);
      float t1 = xlv.y + xrv.y; t1 = fmaxf(t1, 0.2f * t1);
      float t2 = xlv.z + xrv.z; t2 = fmaxf(t2, 0.2f * t2);
      float p = fmaf(t2, c2, fmaf(t1, c1, t0 * c0));
      float mn = fmaxf(m, p);
      float sc = exp2f(m - mn);
      float w  = exp2f(p - mn);
      a0 = a0 * sc + w * xlv.x;
      a1 = a1 * sc + w * xlv.y;
      a2 = a2 * sc + w * xlv.z;
      l = l * sc + w;
      m = mn;
    }
#define MERGE(C)                                                        \
    {                                                                   \
      float m2 = DPP_ROR(C, m);                                         \
      float l2 = DPP_ROR(C, l);                                         \
      float b0 = DPP_ROR(C, a0);                                        \
      float b1v = DPP_ROR(C, a1);                                       \
      float b2v = DPP_ROR(C, a2);                                       \
      float mn = fmaxf(m, m2);                                          \
      float sA = exp2f(m - mn);                                         \
      float sB = exp2f(m2 - mn);                                        \
      a0 = a0 * sA + b0 * sB;                                           \
      a1 = a1 * sA + b1v * sB;                                          \
      a2 = a2 * sA + b2v * sB;                                          \
      l = l * sA + l2 * sB;                                             \
      m = mn;                                                           \
    }
    MERGE(8) MERGE(4) MERGE(2) MERGE(1)
#undef MERGE
    if (lane == 0) {
      float inv = 1.f / (l + 1e-16f);
      float o0 = a0 * inv + b2[0];
      float o1 = a1 * inv + b2[1];
      float o2 = a2 * inv + b2[2];
      int b = batch[node];
      atomicAdd(&ls[b * 3 + 0], o0);
      atomicAdd(&ls[b * 3 + 1], o1);
      atomicAdd(&ls[b * 3 + 2], o2);
      atomicAdd(&lc[b], 1.f);
    }
  }
  __syncthreads();
  for (int i = t; i < NGRAPH * 3; i += 256)
    if (ls[i] != 0.f) atomicAdd(&gsum[i], ls[i]);
  for (int i = t; i < NGRAPH; i += 256)
    if (lc[i] != 0.f) atomicAdd(&gcnt[i], lc[i]);
}

// 1 block, 64 threads: per-graph mean + 2-layer MLP
__global__ __launch_bounds__(64) void k_mlp(const float* __restrict__ gsum,
                                            const float* __restrict__ gcnt,
                                            const float* __restrict__ Wr1,
                                            const float* __restrict__ br1,
                                            const float* __restrict__ Wr2,
                                            const float* __restrict__ br2,
                                            float* __restrict__ out) {
  int t = threadIdx.x;
  if (t >= NGRAPH) return;
  float cnt = fmaxf(gcnt[t], 1.f);
  float g0 = gsum[t * 3 + 0] / cnt;
  float g1 = gsum[t * 3 + 1] / cnt;
  float g2 = gsum[t * 3 + 2] / cnt;
  float o0 = br2[0], o1 = br2[1], o2 = br2[2];
  for (int j = 0; j < 64; ++j) {
    float hj = g0 * Wr1[j] + g1 * Wr1[64 + j] + g2 * Wr1[128 + j] + br1[j];
    hj = fmaxf(hj, 0.f);
    o0 = fmaf(hj, Wr2[j * 3 + 0], o0);
    o1 = fmaf(hj, Wr2[j * 3 + 1], o1);
    o2 = fmaf(hj, Wr2[j * 3 + 2], o2);
  }
  out[t * 3 + 0] = o0;
  out[t * 3 + 1] = o1;
  out[t * 3 + 2] = o2;
}

// ---------------------------------------------------------------------------
extern "C" void kernel_launch(void* const* d_in, const int* in_sizes, int n_in,
                              void* d_out, int out_size, void* d_ws, size_t ws_size,
                              hipStream_t stream) {
  const float* x    = (const float*)d_in[0];
  const int*   ei   = (const int*)d_in[1];
  const int*   batch= (const int*)d_in[2];
  const float* W1l  = (const float*)d_in[3];
  const float* W1r  = (const float*)d_in[4];
  const float* att1 = (const float*)d_in[5];
  const float* b1   = (const float*)d_in[6];
  const float* W2l  = (const float*)d_in[7];
  const float* W2r  = (const float*)d_in[8];
  const float* att2 = (const float*)d_in[9];
  const float* b2   = (const float*)d_in[10];
  const float* Wr1  = (const float*)d_in[11];
  const float* br1  = (const float*)d_in[12];
  const float* Wr2  = (const float*)d_in[13];
  const float* br2  = (const float*)d_in[14];
  float* out = (float*)d_out;

  const int N  = in_sizes[0] / 128;
  const int E  = in_sizes[1] / 2;
  const int Et = E + N;
  const int NB = (N + 1023) / 1024;  // scan blocks (<=64)

  char* p = (char*)d_ws;
  auto alloc = [&](size_t bytes) -> char* {
    char* r = p;
    p += (bytes + 255) & ~(size_t)255;
    return r;
  };
  unsigned short* xl1 = (unsigned short*)alloc((size_t)N * 128 * 2);  // bf16
  float*    xr1    = (float*)alloc((size_t)N * 128 * 4);
  int*      row_ptr= (int*)alloc((size_t)(N + 1) * 4);
  int*      csr_src= (int*)alloc((size_t)Et * 4);
  int*      cursor = (int*)alloc((size_t)N * 4);
  int*      bsum   = (int*)alloc(64 * 4);
  // zero-init group (one memset): deg | gsum | gcnt
  char*     z0     = p;
  int*      deg    = (int*)alloc((size_t)N * 4);
  float*    gsum   = (float*)alloc(NGRAPH * 3 * 4);
  float*    gcnt   = (float*)alloc(NGRAPH * 4);
  size_t    zbytes = (size_t)(p - z0);
  float*    xl2    = (float*)alloc((size_t)N * 4 * 4);
  float*    xr2    = (float*)alloc((size_t)N * 4 * 4);

  hipMemsetAsync(z0, 0, zbytes, stream);
  hipLaunchKernelGGL(k_deg, dim3((Et + 255) / 256), dim3(256), 0, stream, ei, E, Et, deg);
  hipLaunchKernelGGL(k_scan_part, dim3(NB), dim3(256), 0, stream, deg, bsum, N);
  hipLaunchKernelGGL(k_scan_top, dim3(1), dim3(64), 0, stream, bsum, NB);
  hipLaunchKernelGGL(k_scan_write, dim3(NB), dim3(256), 0, stream,
                     deg, bsum, row_ptr, cursor, N);
  hipLaunchKernelGGL(k_fill, dim3((Et + 255) / 256), dim3(256), 0, stream,
                     ei, E, Et, cursor, csr_src);
  hipLaunchKernelGGL(k_gemm128, dim3((N + 63) / 64, 2), dim3(256), 0, stream,
                     x, W1l, W1r, xl1, xr1, N);
  int waves1 = (N + 1) / 2;
  hipLaunchKernelGGL(k_fused1, dim3((waves1 * 64 + 255) / 256), dim3(256), 0, stream,
                     xl1, xr1, row_ptr, csr_src, att1, b1, W2l, W2r, xl2, xr2, N);
  hipLaunchKernelGGL(k_fused2, dim3((N * 16 + 255) / 256), dim3(256), 0, stream,
                     xl2, xr2, row_ptr, csr_src, att2, b2, batch, gsum, gcnt, N);
  hipLaunchKernelGGL(k_mlp, dim3(1), dim3(64), 0, stream,
                     gsum, gcnt, Wr1, br1, Wr2, br2, out);
}

// Round 13
// 285.707 us; speedup vs baseline: 2.0266x; 1.1401x over previous
//
#include <hip/hip_runtime.h>

// ---------------------------------------------------------------------------
// GATv2 (2 layers) + mean-pool + MLP for MI355X.
// N=50000 nodes, E=800000 edges (+N self loops), IN=128, HID=64, HEADS=2,
// OUT=3, 64 graphs. Output: [64,3] float32.
// R1: k_agg2 pool atomic storm fixed (LDS pre-reduction). 1128 -> 803 us.
// R2: CSR + per-node online softmax; edge phases fused.   803 -> 515 us.
// R3: fused1 2-edge ILP + reg src cache + W2-proj fused.   515 -> 394 us.
// R4: fused1 2 nodes/wave + 4-edge ILP + batched softmax.  394 -> 368 us.
// R5: gemm 128x128 reg-blocked (LDS 72KB->16KB).            368 -> 343 us.
// R6: DPP rotate-reduce + exp2 domain; gemm 64x128/4x8.     343 -> 337 us.
// R7: 8-edge unroll flat. R8-R10: degree-sort detour regressed; reverted.
// R11: 3-phase parallel scan (single-block scan was 100us!). 422 -> 329 us.
// R12: xl1 message table bf16 (gather 512->256B/edge).       329 -> 326 us,
//     fused1 off top-5; revealed k_fill 61us (atomic->store latency chain)
//     and k_gemm128 61us (2 dispatches, 32 FMA per 3 ds_read, occ 23%).
// R13: k_fill atomic-free — k_deg's atomicAdd RETURN is the rank; k_fill is
//     gather+store only. gemm merged: one dispatch does x@W1l AND x@W1r per
//     x-tile (64 FMA per 5 ds_read, x read once). Bit-identical math.
// ---------------------------------------------------------------------------

#define NGRAPH 64
#define LOG2E 1.4426950408889634f

// v_mov_dpp row_ror:k (16-lane rows). Valid reduce permutation for
// commutative ops; leaves every lane of the row with the full result.
#define DPP_ROR(C, x) \
  __int_as_float(__builtin_amdgcn_update_dpp(0, __float_as_int(x), (0x120 | C), 0xF, 0xF, false))

__device__ __forceinline__ float rowsum16(float v) {
  v += DPP_ROR(8, v);
  v += DPP_ROR(4, v);
  v += DPP_ROR(2, v);
  v += DPP_ROR(1, v);
  return v;
}

__device__ __forceinline__ unsigned bf16rne(float f) {
  unsigned u = __float_as_uint(f);
  return (u + 0x7FFFu + ((u >> 16) & 1u)) >> 16;
}

// ---------------------------------------------------------------------------
// R13: the atomic's return value IS this edge's rank among its dst's edges.
__global__ void k_deg(const int* __restrict__ ei, int E, int Et,
                      int* __restrict__ deg, int* __restrict__ rank) {
  int e = blockIdx.x * blockDim.x + threadIdx.x;
  if (e >= Et) return;
  int d = (e < E) ? ei[E + e] : (e - E);  // dst only
  rank[e] = atomicAdd(&deg[d], 1);        // coalesced store of the rank
}

// ---------------------------------------------------------------------------
// 3-phase parallel exclusive scan of deg[0..n) -> row_ptr[0..n].
__global__ __launch_bounds__(256) void k_scan_part(const int* __restrict__ deg,
                                                   int* __restrict__ bsum, int n) {
  __shared__ int sd[256];
  int t = threadIdx.x;
  int i = blockIdx.x * 1024 + t * 4;
  int s = 0;
  if (i + 4 <= n) {
    int4 d = *(const int4*)&deg[i];
    s = d.x + d.y + d.z + d.w;
  } else {
    for (int j = i; j < min(i + 4, n); ++j) s += deg[j];
  }
  sd[t] = s;
  __syncthreads();
  for (int off = 128; off; off >>= 1) {
    if (t < off) sd[t] += sd[t + off];
    __syncthreads();
  }
  if (t == 0) bsum[blockIdx.x] = sd[0];
}

__global__ __launch_bounds__(64) void k_scan_top(int* __restrict__ bsum, int nb) {
  __shared__ int s[64];
  int t = threadIdx.x;
  s[t] = (t < nb) ? bsum[t] : 0;
  __syncthreads();
  int acc = 0;
  for (int j = 0; j < t; ++j) acc += s[j];
  if (t < nb) bsum[t] = acc;
}

__global__ __launch_bounds__(256) void k_scan_write(const int* __restrict__ deg,
                                                    const int* __restrict__ bsum,
                                                    int* __restrict__ row_ptr, int n) {
  __shared__ int sd[256];
  int t = threadIdx.x;
  int i = blockIdx.x * 1024 + t * 4;
  int4 d = make_int4(0, 0, 0, 0);
  bool full = (i + 4 <= n);
  if (full) d = *(const int4*)&deg[i];
  else {
    if (i + 0 < n) d.x = deg[i + 0];
    if (i + 1 < n) d.y = deg[i + 1];
    if (i + 2 < n) d.z = deg[i + 2];
    if (i + 3 < n) d.w = deg[i + 3];
  }
  int s = d.x + d.y + d.z + d.w;
  sd[t] = s;
  __syncthreads();
  for (int off = 1; off < 256; off <<= 1) {  // Hillis-Steele inclusive
    int v = (t >= off) ? sd[t - off] : 0;
    __syncthreads();
    sd[t] += v;
    __syncthreads();
  }
  int ex = sd[t] - s + bsum[blockIdx.x];
  int4 r;
  r.x = ex;
  r.y = ex + d.x;
  r.z = r.y + d.y;
  r.w = r.z + d.z;
  if (full) {
    *(int4*)&row_ptr[i] = r;
    if (i + 4 == n) row_ptr[n] = r.w + d.w;
  } else if (i < n) {
    int run = ex;
    int vals[4] = {d.x, d.y, d.z, d.w};
    for (int j = 0; j < 4 && i + j < n; ++j) {
      row_ptr[i + j] = run;
      run += vals[j];
    }
    if (i <= n && i + 4 > n) row_ptr[n] = run;
  }
}

// R13: no atomic — slot is row_ptr[d] + precomputed rank.
__global__ void k_fill(const int* __restrict__ ei, int E, int Et,
                       const int* __restrict__ row_ptr,
                       const int* __restrict__ rank,
                       int* __restrict__ csr_src) {
  int e = blockIdx.x * blockDim.x + threadIdx.x;
  if (e >= Et) return;
  int s, d;
  if (e < E) { s = ei[e]; d = ei[E + e]; }
  else       { s = e - E; d = s; }
  csr_src[row_ptr[d] + rank[e]] = s;
}

// ---------------------------------------------------------------------------
// R13 merged: one dispatch computes xl1 = x@W1l (stored BF16) AND
// xr1 = x@W1r (fp32) per 64-row x tile. x staged once; both W tiles in LDS;
// per k: 5 ds_read_b128 feed 64 FMA. Bit-identical to the two-pass version.
__global__ __launch_bounds__(256) void k_gemm128(const float* __restrict__ x,
                                                 const float* __restrict__ Wl,
                                                 const float* __restrict__ Wr,
                                                 unsigned short* __restrict__ outl,
                                                 float* __restrict__ outr, int n) {
  __shared__ __align__(16) float xs[16][68];    // x tile transposed: [k][row]
  __shared__ __align__(16) float wsl[16][132];  // W1l tile: [k][col]
  __shared__ __align__(16) float wsr[16][132];  // W1r tile: [k][col]
  int t = threadIdx.x;
  int tx = t & 15, ty = t >> 4;
  int r0 = blockIdx.x * 64;
  float accl[4][8] = {};
  float accr[4][8] = {};

  int sr = t >> 2;           // x staging: row 0..63
  int sk = (t & 3) * 4;      // k-quad
  int wk = t >> 5;           // W staging: k row 0..7
  int wc = (t & 31) * 4;     // col quad

  for (int k0 = 0; k0 < 128; k0 += 16) {
    int gr = r0 + sr;
    float4 xv = make_float4(0.f, 0.f, 0.f, 0.f);
    if (gr < n) xv = *(const float4*)&x[(size_t)gr * 128 + k0 + sk];
    float4 wl0 = *(const float4*)&Wl[(size_t)(k0 + wk) * 128 + wc];
    float4 wl1 = *(const float4*)&Wl[(size_t)(k0 + wk + 8) * 128 + wc];
    float4 wr0 = *(const float4*)&Wr[(size_t)(k0 + wk) * 128 + wc];
    float4 wr1 = *(const float4*)&Wr[(size_t)(k0 + wk + 8) * 128 + wc];
    __syncthreads();
    xs[sk + 0][sr] = xv.x;
    xs[sk + 1][sr] = xv.y;
    xs[sk + 2][sr] = xv.z;
    xs[sk + 3][sr] = xv.w;
    *(float4*)&wsl[wk][wc] = wl0;
    *(float4*)&wsl[wk + 8][wc] = wl1;
    *(float4*)&wsr[wk][wc] = wr0;
    *(float4*)&wsr[wk + 8][wc] = wr1;
    __syncthreads();
#pragma unroll
    for (int k = 0; k < 16; ++k) {
      float4 av = *(const float4*)&xs[k][ty * 4];
      float4 bl0 = *(const float4*)&wsl[k][tx * 4];
      float4 bl1 = *(const float4*)&wsl[k][64 + tx * 4];
      float4 br0 = *(const float4*)&wsr[k][tx * 4];
      float4 br1 = *(const float4*)&wsr[k][64 + tx * 4];
      float a[4] = {av.x, av.y, av.z, av.w};
      float bl[8] = {bl0.x, bl0.y, bl0.z, bl0.w, bl1.x, bl1.y, bl1.z, bl1.w};
      float br[8] = {br0.x, br0.y, br0.z, br0.w, br1.x, br1.y, br1.z, br1.w};
#pragma unroll
      for (int i = 0; i < 4; ++i)
#pragma unroll
        for (int j = 0; j < 8; ++j) {
          accl[i][j] = fmaf(a[i], bl[j], accl[i][j]);
          accr[i][j] = fmaf(a[i], br[j], accr[i][j]);
        }
    }
  }
#pragma unroll
  for (int i = 0; i < 4; ++i) {
    int gr = r0 + ty * 4 + i;
    if (gr < n) {
      uint2 p0, p1;
      p0.x = bf16rne(accl[i][0]) | (bf16rne(accl[i][1]) << 16);
      p0.y = bf16rne(accl[i][2]) | (bf16rne(accl[i][3]) << 16);
      p1.x = bf16rne(accl[i][4]) | (bf16rne(accl[i][5]) << 16);
      p1.y = bf16rne(accl[i][6]) | (bf16rne(accl[i][7]) << 16);
      *(uint2*)&outl[(size_t)gr * 128 + tx * 4] = p0;
      *(uint2*)&outl[(size_t)gr * 128 + 64 + tx * 4] = p1;
      *(float4*)&outr[(size_t)gr * 128 + tx * 4] =
          make_float4(accr[i][0], accr[i][1], accr[i][2], accr[i][3]);
      *(float4*)&outr[(size_t)gr * 128 + 64 + tx * 4] =
          make_float4(accr[i][4], accr[i][5], accr[i][6], accr[i][7]);
    }
  }
}

// ---------------------------------------------------------------------------
// fused layer-1 edge phase + layer-2 input projection.
// TWO nodes per wave: lanes 0-31 = node 2w, 32-63 = node 2w+1. Lane holds 4
// channels; 16-lane head groups = DPP rows. 4 edges/iter: clamp-free main
// loop to mindeg, clamped+masked tail to maxdeg. xl gathered as BF16x4
// (uint2, 8B/lane = 256B/row) and unpacked with shift/mask; acc fp32.
__global__ __launch_bounds__(256) void k_fused1(const unsigned short* __restrict__ xl,
                                                const float* __restrict__ xr,
                                                const int* __restrict__ row_ptr,
                                                const int* __restrict__ csr_src,
                                                const float* __restrict__ att1,
                                                const float* __restrict__ b1,
                                                const float* __restrict__ W2l,
                                                const float* __restrict__ W2r,
                                                float* __restrict__ xl2,
                                                float* __restrict__ xr2, int n) {
  int wid  = (blockIdx.x * 256 + threadIdx.x) >> 6;
  int lane = threadIdx.x & 63;
  int sub  = lane & 31;
  int node = min(wid * 2 + (lane >> 5), n - 1);  // dup of last node is benign
  int ch = sub * 4;
  const char* xlb = (const char*)xl;
  unsigned chb = (unsigned)sub * 8u;  // byte offset within 256B bf16 row
  float4 xrv = *(const float4*)&xr[(size_t)node * 128 + ch];
  float4 atv = *(const float4*)&att1[ch];
  atv.x *= LOG2E; atv.y *= LOG2E; atv.z *= LOG2E; atv.w *= LOG2E;
  int s0 = row_ptr[node];
  int deg = row_ptr[node + 1] - s0;  // >=1 (self-loop)
  int odeg = __shfl_xor(deg, 32);
  int mindeg = min(deg, odeg);  // wave-uniform
  int maxdeg = max(deg, odeg);  // wave-uniform
  const int* sp = csr_src + s0;

  float m = -1e30f, l = 0.f;
  float4 acc = make_float4(0.f, 0.f, 0.f, 0.f);

  float t0, t1, t2, t3;
#define UNPACK(dst, q)                                                  \
    dst.x = __uint_as_float(q.x << 16);                                 \
    dst.y = __uint_as_float(q.x & 0xFFFF0000u);                         \
    dst.z = __uint_as_float(q.y << 16);                                 \
    dst.w = __uint_as_float(q.y & 0xFFFF0000u);
#define LOGIT(p, v)                                                     \
    t0 = v.x + xrv.x; t0 = fmaxf(t0, 0.2f * t0);                        \
    t1 = v.y + xrv.y; t1 = fmaxf(t1, 0.2f * t1);                        \
    t2 = v.z + xrv.z; t2 = fmaxf(t2, 0.2f * t2);                        \
    t3 = v.w + xrv.w; t3 = fmaxf(t3, 0.2f * t3);                        \
    p = fmaf(t3, atv.w, fmaf(t2, atv.z, fmaf(t1, atv.y, t0 * atv.x)));

#define BODY(CLAMPED)                                                   \
  {                                                                     \
    int sA, sB, sC, sD;                                                 \
    if (CLAMPED) {                                                      \
      int dm1 = deg - 1;                                                \
      sA = sp[min(e + 0, dm1)];                                         \
      sB = sp[min(e + 1, dm1)];                                         \
      sC = sp[min(e + 2, dm1)];                                         \
      sD = sp[min(e + 3, dm1)];                                         \
    } else {                                                            \
      sA = sp[e + 0]; sB = sp[e + 1]; sC = sp[e + 2]; sD = sp[e + 3];   \
    }                                                                   \
    uint2 qa = *(const uint2*)(xlb + (((unsigned)sA << 8) + chb));      \
    uint2 qb = *(const uint2*)(xlb + (((unsigned)sB << 8) + chb));      \
    uint2 qc = *(const uint2*)(xlb + (((unsigned)sC << 8) + chb));      \
    uint2 qd = *(const uint2*)(xlb + (((unsigned)sD << 8) + chb));      \
    float4 xa, xb, xc, xd;                                              \
    UNPACK(xa, qa) UNPACK(xb, qb) UNPACK(xc, qc) UNPACK(xd, qd)         \
    float pa, pb, pc, pd;                                               \
    LOGIT(pa, xa) LOGIT(pb, xb) LOGIT(pc, xc) LOGIT(pd, xd)             \
    pa = rowsum16(pa);                                                  \
    pb = rowsum16(pb);                                                  \
    pc = rowsum16(pc);                                                  \
    pd = rowsum16(pd);                                                  \
    if (CLAMPED) {                                                      \
      pa = (e + 0 < deg) ? pa : -1e30f;                                 \
      pb = (e + 1 < deg) ? pb : -1e30f;                                 \
      pc = (e + 2 < deg) ? pc : -1e30f;                                 \
      pd = (e + 3 < deg) ? pd : -1e30f;                                 \
    }                                                                   \
    float mn = fmaxf(m, fmaxf(fmaxf(pa, pb), fmaxf(pc, pd)));           \
    float sc = exp2f(m - mn);                                           \
    float wa = exp2f(pa - mn);                                          \
    float wb = exp2f(pb - mn);                                          \
    float wc = exp2f(pc - mn);                                          \
    float wd = exp2f(pd - mn);                                          \
    acc.x = fmaf(wd, xd.x, fmaf(wc, xc.x, fmaf(wb, xb.x, fmaf(wa, xa.x, acc.x * sc)))); \
    acc.y = fmaf(wd, xd.y, fmaf(wc, xc.y, fmaf(wb, xb.y, fmaf(wa, xa.y, acc.y * sc)))); \
    acc.z = fmaf(wd, xd.z, fmaf(wc, xc.z, fmaf(wb, xb.z, fmaf(wa, xa.z, acc.z * sc)))); \
    acc.w = fmaf(wd, xd.w, fmaf(wc, xc.w, fmaf(wb, xb.w, fmaf(wa, xa.w, acc.w * sc)))); \
    l = fmaf(l, sc, wa + wb + wc + wd);                                 \
    m = mn;                                                             \
  }

  int e = 0;
  for (; e + 4 <= mindeg; e += 4) BODY(false)
  for (; e < maxdeg; e += 4) BODY(true)
#undef BODY
#undef LOGIT
#undef UNPACK

  float inv = 1.f / (l + 1e-16f);
  float4 b1v = *(const float4*)&b1[ch];
  float4 h;
  h.x = acc.x * inv + b1v.x; h.x = h.x > 0.f ? h.x : expm1f(h.x);
  h.y = acc.y * inv + b1v.y; h.y = h.y > 0.f ? h.y : expm1f(h.y);
  h.z = acc.z * inv + b1v.z; h.z = h.z > 0.f ? h.z : expm1f(h.z);
  h.w = acc.w * inv + b1v.w; h.w = h.w > 0.f ? h.w : expm1f(h.w);

  float4 u0 = *(const float4*)&W2l[ch * 3 + 0];
  float4 u1 = *(const float4*)&W2l[ch * 3 + 4];
  float4 u2 = *(const float4*)&W2l[ch * 3 + 8];
  float al0 = fmaf(h.w, u2.y, fmaf(h.z, u1.z, fmaf(h.y, u0.w, h.x * u0.x)));
  float al1 = fmaf(h.w, u2.z, fmaf(h.z, u1.w, fmaf(h.y, u1.x, h.x * u0.y)));
  float al2 = fmaf(h.w, u2.w, fmaf(h.z, u2.x, fmaf(h.y, u1.y, h.x * u0.z)));
  float4 v0 = *(const float4*)&W2r[ch * 3 + 0];
  float4 v1 = *(const float4*)&W2r[ch * 3 + 4];
  float4 v2 = *(const float4*)&W2r[ch * 3 + 8];
  float ar0 = fmaf(h.w, v2.y, fmaf(h.z, v1.z, fmaf(h.y, v0.w, h.x * v0.x)));
  float ar1 = fmaf(h.w, v2.z, fmaf(h.z, v1.w, fmaf(h.y, v1.x, h.x * v0.y)));
  float ar2 = fmaf(h.w, v2.w, fmaf(h.z, v2.x, fmaf(h.y, v1.y, h.x * v0.z)));
#pragma unroll
  for (int off = 1; off < 32; off <<= 1) {
    al0 += __shfl_xor(al0, off); al1 += __shfl_xor(al1, off);
    al2 += __shfl_xor(al2, off); ar0 += __shfl_xor(ar0, off);
    ar1 += __shfl_xor(ar1, off); ar2 += __shfl_xor(ar2, off);
  }
  if (sub == 0 && wid * 2 + (lane >> 5) < n) {
    *(float4*)&xl2[node * 4] = make_float4(al0, al1, al2, 0.f);
    *(float4*)&xr2[node * 4] = make_float4(ar0, ar1, ar2, 0.f);
  }
}

// ---------------------------------------------------------------------------
// fused layer-2 edge phase + mean-pool. 16 lanes per node (= one DPP row);
// per-lane online softmax (exp2 domain) over a 16-stride slice, DPP rotate
// merge of (m,l,acc3) states. Pool pre-reduced in LDS.
__global__ __launch_bounds__(256) void k_fused2(const float* __restrict__ xl2,
                                                const float* __restrict__ xr2,
                                                const int* __restrict__ row_ptr,
                                                const int* __restrict__ csr_src,
                                                const float* __restrict__ att2,
                                                const float* __restrict__ b2,
                                                const int* __restrict__ batch,
                                                float* __restrict__ gsum,
                                                float* __restrict__ gcnt, int n) {
  __shared__ float ls[NGRAPH * 3];
  __shared__ float lc[NGRAPH];
  int t = threadIdx.x;
  for (int i = t; i < NGRAPH * 3; i += 256) ls[i] = 0.f;
  for (int i = t; i < NGRAPH; i += 256) lc[i] = 0.f;
  __syncthreads();

  int node = (blockIdx.x * 256 + t) >> 4;  // 16 nodes per block
  int lane = t & 15;
  if (node < n) {
    float4 xrv = *(const float4*)&xr2[node * 4];
    float c0 = att2[0] * LOG2E, c1 = att2[1] * LOG2E, c2 = att2[2] * LOG2E;
    int s0 = row_ptr[node], s1 = row_ptr[node + 1];
    float m = -1e30f, l = 0.f, a0 = 0.f, a1 = 0.f, a2 = 0.f;
    for (int slot = s0 + lane; slot < s1; slot += 16) {
      int s = csr_src[slot];
      float4 xlv = *(const float4*)&xl2[s * 4];
      float t0 = xlv.x + xrv.x; t0 = fmaxf(t0, 0.2f * t0);
      float t1 = xlv.y + xrv.y; t1 = fmaxf(t1, 0.2f * t1);
      float t2 = xlv.z + xrv.z; t2 = fmaxf(t2, 0.2f * t2);
      float p = fmaf(t2, c2, fmaf(t1, c1, t0 * c0));
      float mn = fmaxf(m, p);
      float sc = exp2f(m - mn);
      float w  = exp2f(p - mn);
      a0 = a0 * sc + w * xlv.x;
      a1 = a1 * sc + w * xlv.y;
      a2 = a2 * sc + w * xlv.z;
      l = l * sc + w;
      m = mn;
    }
#define MERGE(C)                                                        \
    {                                                                   \
      float m2 = DPP_ROR(C, m);                                         \
      float l2 = DPP_ROR(C, l);                                         \
      float b0 = DPP_ROR(C, a0);                                        \
      float b1v = DPP_ROR(C, a1);                                       \
      float b2v = DPP_ROR(C, a2);                                       \
      float mn = fmaxf(m, m2);                                          \
      float sA = exp2f(m - mn);                                         \
      float sB = exp2f(m2 - mn);                                        \
      a0 = a0 * sA + b0 * sB;                                           \
      a1 = a1 * sA + b1v * sB;                                          \
      a2 = a2 * sA + b2v * sB;                                          \
      l = l * sA + l2 * sB;                                             \
      m = mn;                                                           \
    }
    MERGE(8) MERGE(4) MERGE(2) MERGE(1)
#undef MERGE
    if (lane == 0) {
      float inv = 1.f / (l + 1e-16f);
      float o0 = a0 * inv + b2[0];
      float o1 = a1 * inv + b2[1];
      float o2 = a2 * inv + b2[2];
      int b = batch[node];
      atomicAdd(&ls[b * 3 + 0], o0);
      atomicAdd(&ls[b * 3 + 1], o1);
      atomicAdd(&ls[b * 3 + 2], o2);
      atomicAdd(&lc[b], 1.f);
    }
  }
  __syncthreads();
  for (int i = t; i < NGRAPH * 3; i += 256)
    if (ls[i] != 0.f) atomicAdd(&gsum[i], ls[i]);
  for (int i = t; i < NGRAPH; i += 256)
    if (lc[i] != 0.f) atomicAdd(&gcnt[i], lc[i]);
}

// 1 block, 64 threads: per-graph mean + 2-layer MLP
__global__ __launch_bounds__(64) void k_mlp(const float* __restrict__ gsum,
                                            const float* __restrict__ gcnt,
                                            const float* __restrict__ Wr1,
                                            const float* __restrict__ br1,
                                            const float* __restrict__ Wr2,
                                            const float* __restrict__ br2,
                                            float* __restrict__ out) {
  int t = threadIdx.x;
  if (t >= NGRAPH) return;
  float cnt = fmaxf(gcnt[t], 1.f);
  float g0 = gsum[t * 3 + 0] / cnt;
  float g1 = gsum[t * 3 + 1] / cnt;
  float g2 = gsum[t * 3 + 2] / cnt;
  float o0 = br2[0], o1 = br2[1], o2 = br2[2];
  for (int j = 0; j < 64; ++j) {
    float hj = g0 * Wr1[j] + g1 * Wr1[64 + j] + g2 * Wr1[128 + j] + br1[j];
    hj = fmaxf(hj, 0.f);
    o0 = fmaf(hj, Wr2[j * 3 + 0], o0);
    o1 = fmaf(hj, Wr2[j * 3 + 1], o1);
    o2 = fmaf(hj, Wr2[j * 3 + 2], o2);
  }
  out[t * 3 + 0] = o0;
  out[t * 3 + 1] = o1;
  out[t * 3 + 2] = o2;
}

// ---------------------------------------------------------------------------
extern "C" void kernel_launch(void* const* d_in, const int* in_sizes, int n_in,
                              void* d_out, int out_size, void* d_ws, size_t ws_size,
                              hipStream_t stream) {
  const float* x    = (const float*)d_in[0];
  const int*   ei   = (const int*)d_in[1];
  const int*   batch= (const int*)d_in[2];
  const float* W1l  = (const float*)d_in[3];
  const float* W1r  = (const float*)d_in[4];
  const float* att1 = (const float*)d_in[5];
  const float* b1   = (const float*)d_in[6];
  const float* W2l  = (const float*)d_in[7];
  const float* W2r  = (const float*)d_in[8];
  const float* att2 = (const float*)d_in[9];
  const float* b2   = (const float*)d_in[10];
  const float* Wr1  = (const float*)d_in[11];
  const float* br1  = (const float*)d_in[12];
  const float* Wr2  = (const float*)d_in[13];
  const float* br2  = (const float*)d_in[14];
  float* out = (float*)d_out;

  const int N  = in_sizes[0] / 128;
  const int E  = in_sizes[1] / 2;
  const int Et = E + N;
  const int NB = (N + 1023) / 1024;  // scan blocks (<=64)

  char* p = (char*)d_ws;
  auto alloc = [&](size_t bytes) -> char* {
    char* r = p;
    p += (bytes + 255) & ~(size_t)255;
    return r;
  };
  unsigned short* xl1 = (unsigned short*)alloc((size_t)N * 128 * 2);  // bf16
  float*    xr1    = (float*)alloc((size_t)N * 128 * 4);
  int*      row_ptr= (int*)alloc((size_t)(N + 1) * 4);
  int*      csr_src= (int*)alloc((size_t)Et * 4);
  int*      rank   = (int*)alloc((size_t)Et * 4);
  int*      bsum   = (int*)alloc(64 * 4);
  // zero-init group (one memset): deg | gsum | gcnt
  char*     z0     = p;
  int*      deg    = (int*)alloc((size_t)N * 4);
  float*    gsum   = (float*)alloc(NGRAPH * 3 * 4);
  float*    gcnt   = (float*)alloc(NGRAPH * 4);
  size_t    zbytes = (size_t)(p - z0);
  float*    xl2    = (float*)alloc((size_t)N * 4 * 4);
  float*    xr2    = (float*)alloc((size_t)N * 4 * 4);

  hipMemsetAsync(z0, 0, zbytes, stream);
  hipLaunchKernelGGL(k_deg, dim3((Et + 255) / 256), dim3(256), 0, stream,
                     ei, E, Et, deg, rank);
  hipLaunchKernelGGL(k_scan_part, dim3(NB), dim3(256), 0, stream, deg, bsum, N);
  hipLaunchKernelGGL(k_scan_top, dim3(1), dim3(64), 0, stream, bsum, NB);
  hipLaunchKernelGGL(k_scan_write, dim3(NB), dim3(256), 0, stream,
                     deg, bsum, row_ptr, N);
  hipLaunchKernelGGL(k_fill, dim3((Et + 255) / 256), dim3(256), 0, stream,
                     ei, E, Et, row_ptr, rank, csr_src);
  hipLaunchKernelGGL(k_gemm128, dim3((N + 63) / 64), dim3(256), 0, stream,
                     x, W1l, W1r, xl1, xr1, N);
  int waves1 = (N + 1) / 2;
  hipLaunchKernelGGL(k_fused1, dim3((waves1 * 64 + 255) / 256), dim3(256), 0, stream,
                     xl1, xr1, row_ptr, csr_src, att1, b1, W2l, W2r, xl2, xr2, N);
  hipLaunchKernelGGL(k_fused2, dim3((N * 16 + 255) / 256), dim3(256), 0, stream,
                     xl2, xr2, row_ptr, csr_src, att2, b2, batch, gsum, gcnt, N);
  hipLaunchKernelGGL(k_mlp, dim3(1), dim3(64), 0, stream,
                     gsum, gcnt, Wr1, br1, Wr2, br2, out);
}